// Round 12
// baseline (219.250 us; speedup 1.0000x reference)
//
#include <hip/hip_runtime.h>

typedef __attribute__((ext_vector_type(8))) short short8;
typedef __attribute__((ext_vector_type(4))) float f32x4;
typedef __attribute__((ext_vector_type(16))) float f32x16;

#define S_LEN 2048
#define HIDN  1024
#define NHEAD 16
#define DHEAD 64

__device__ __forceinline__ short f2bf(float x) {
    unsigned u = __float_as_uint(x);
    u += 0x7fffu + ((u >> 16) & 1u);
    return (short)(u >> 16);
}

typedef const __attribute__((address_space(1))) void* gas_ptr;
typedef __attribute__((address_space(3))) void* las_ptr;

__device__ __forceinline__ void gload_lds16(const void* g, void* l) {
    __builtin_amdgcn_global_load_lds((gas_ptr)g, (las_ptr)l, 16, 0, 0);
}

__device__ __forceinline__ unsigned cvtpk(float lo, float hi_) {
    unsigned r;
    asm("v_cvt_pk_bf16_f32 %0, %1, %2" : "=v"(r) : "v"(lo), "v"(hi_));
    return r;
}

__device__ __forceinline__ void plswap(unsigned& x, unsigned& y) {
    asm("v_permlane32_swap_b32 %0, %1" : "+&v"(x), "+&v"(y));
}

__device__ __forceinline__ short8 mk8(unsigned a, unsigned b, unsigned c, unsigned d) {
    union { unsigned u[4]; short8 s; } t;
    t.u[0] = a; t.u[1] = b; t.u[2] = c; t.u[3] = d;
    return t.s;
}

// ---------------- fp32 -> bf16: 3 activations (4096 blocks each) + 4 weights (512 each) ----------------
__global__ __launch_bounds__(256) void cvt_all(const float* __restrict__ q,
                                               const float* __restrict__ k,
                                               const float* __restrict__ v,
                                               const float* __restrict__ Wq,
                                               const float* __restrict__ Wk,
                                               const float* __restrict__ Wv,
                                               const float* __restrict__ Wo,
                                               short* __restrict__ qb,
                                               short* __restrict__ kb,
                                               short* __restrict__ vb,
                                               short* __restrict__ wqb,
                                               short* __restrict__ wkb,
                                               short* __restrict__ wvb,
                                               short* __restrict__ wob) {
    int bid = blockIdx.x;
    const float* in;
    short* out;
    int base;
    if (bid < 4096)       { in = q; out = qb; base = bid; }
    else if (bid < 8192)  { in = k; out = kb; base = bid - 4096; }
    else if (bid < 12288) { in = v; out = vb; base = bid - 8192; }
    else {
        int t = bid - 12288;
        int wsel = t >> 9;
        base = t & 511;
        in  = wsel == 0 ? Wq  : wsel == 1 ? Wk  : wsel == 2 ? Wv  : Wo;
        out = wsel == 0 ? wqb : wsel == 1 ? wkb : wsel == 2 ? wvb : wob;
    }
    int i = (base * 256 + threadIdx.x) * 8;
    float4 a = *(const float4*)(in + i);
    float4 b = *(const float4*)(in + i + 4);
    short8 o;
    o[0] = f2bf(a.x); o[1] = f2bf(a.y); o[2] = f2bf(a.z); o[3] = f2bf(a.w);
    o[4] = f2bf(b.x); o[5] = f2bf(b.y); o[6] = f2bf(b.z); o[7] = f2bf(b.w);
    *(short8*)(out + i) = o;
}

// ---------------- GEMM core: bf16 x bf16, 2-PHASE double-buffered LDS ----------------
// Loop: STAGE(buf^1, kt+1) -> ds_read+MFMA on buf -> __syncthreads (drains vmcnt: next
// tile landed; barrier: all waves done reading buf^1 from last iter). Loads for kt+1
// are in flight DURING kt's MFMA -> HBM/L2 latency hidden by compute (T3-minimum).
__device__ __forceinline__ void gemm_body_bf16(const short* A, const short* Wb,
                                               const float* bias, short* Out,
                                               float oscale, int omode, int bid) {
    int mt = bid & 63;
    int nt = bid >> 6;
    int m0 = mt * 128, n0 = nt * 128;
    int tid = threadIdx.x;
    int w = tid >> 6, l = tid & 63, g = l >> 4, r = l & 15;
    int wm = w >> 1, wn = w & 1;

    __shared__ short As[2][128 * 32];
    __shared__ short Bs[2][128 * 32];

    int c0 = w, c1 = w + 4;                 // this thread's two staging chunks
    int o0 = c0 * 1024 + l * 16, o1 = c1 * 1024 + l * 16;
    int row0 = o0 >> 6, col0 = (o0 & 63) >> 1;
    int row1 = o1 >> 6, col1 = (o1 & 63) >> 1;

    f32x4 acc[4][4];
#pragma unroll
    for (int i = 0; i < 4; i++)
#pragma unroll
        for (int j = 0; j < 4; j++) acc[i][j] = (f32x4){0.f, 0.f, 0.f, 0.f};

    // prologue: stage tile 0 into buf 0
    gload_lds16(A + (size_t)(m0 + row0) * HIDN + col0, &As[0][c0 * 512]);
    gload_lds16(Wb + (size_t)(n0 + row0) * HIDN + col0, &Bs[0][c0 * 512]);
    gload_lds16(A + (size_t)(m0 + row1) * HIDN + col1, &As[0][c1 * 512]);
    gload_lds16(Wb + (size_t)(n0 + row1) * HIDN + col1, &Bs[0][c1 * 512]);
    __syncthreads();

    int cur = 0;
    for (int kt = 0; kt < HIDN / 32; ++kt) {
        if (kt + 1 < HIDN / 32) {  // issue next-tile loads; they fly during this MFMA block
            int nb = cur ^ 1, kc = (kt + 1) * 32;
            gload_lds16(A + (size_t)(m0 + row0) * HIDN + kc + col0, &As[nb][c0 * 512]);
            gload_lds16(Wb + (size_t)(n0 + row0) * HIDN + kc + col0, &Bs[nb][c0 * 512]);
            gload_lds16(A + (size_t)(m0 + row1) * HIDN + kc + col1, &As[nb][c1 * 512]);
            gload_lds16(Wb + (size_t)(n0 + row1) * HIDN + kc + col1, &Bs[nb][c1 * 512]);
        }
        short8 af[4], bfr[4];
#pragma unroll
        for (int i = 0; i < 4; i++)
            af[i] = *(const short8*)(&As[cur][(wm * 64 + i * 16 + r) * 32 + g * 8]);
#pragma unroll
        for (int j = 0; j < 4; j++)
            bfr[j] = *(const short8*)(&Bs[cur][(wn * 64 + j * 16 + r) * 32 + g * 8]);
        __builtin_amdgcn_s_setprio(1);
#pragma unroll
        for (int i = 0; i < 4; i++)
#pragma unroll
            for (int j = 0; j < 4; j++)
                acc[i][j] = __builtin_amdgcn_mfma_f32_16x16x32_bf16(af[i], bfr[j], acc[i][j], 0, 0, 0);
        __builtin_amdgcn_s_setprio(0);
        __syncthreads();  // vmcnt(0): next tile landed; barrier: buf reads done
        cur ^= 1;
    }

#pragma unroll
    for (int j = 0; j < 4; j++) {
        int n_g = n0 + wn * 64 + j * 16 + r;
        float bv = bias[n_g];
        int h = n_g >> 6, d = n_g & 63;
#pragma unroll
        for (int i = 0; i < 4; i++) {
#pragma unroll
            for (int rr = 0; rr < 4; rr++) {
                int m_g = m0 + wm * 64 + i * 16 + g * 4 + rr;
                float val = (acc[i][j][rr] + bv) * oscale;
                int b = m_g >> 11, s = m_g & 2047;
                size_t idx = (omode == 0)
                    ? (((size_t)(b * NHEAD + h)) * S_LEN + s) * DHEAD + d
                    : (((size_t)(b * NHEAD + h)) * DHEAD + d) * S_LEN + s;
                Out[idx] = f2bf(val);
            }
        }
    }
}

__global__ __launch_bounds__(256) void gemm_qkv(const short* __restrict__ qb,
                                                const short* __restrict__ kb,
                                                const short* __restrict__ vb,
                                                const short* __restrict__ Wqb,
                                                const short* __restrict__ Wkb,
                                                const short* __restrict__ Wvb,
                                                const float* __restrict__ bq,
                                                const float* __restrict__ bk,
                                                const float* __restrict__ bv,
                                                short* __restrict__ Qh,
                                                short* __restrict__ Kh,
                                                short* __restrict__ VhT,
                                                float qscale) {
    int which = blockIdx.x >> 9;
    int bid = blockIdx.x & 511;
    const short* A = which == 0 ? qb : which == 1 ? kb : vb;
    const short* Wb = which == 0 ? Wqb : which == 1 ? Wkb : Wvb;
    const float* bias = which == 0 ? bq : which == 1 ? bk : bv;
    short* Out = which == 0 ? Qh : which == 1 ? Kh : VhT;
    float oscale = which == 0 ? qscale : 1.0f;
    int omode = which == 2 ? 1 : 0;
    gemm_body_bf16(A, Wb, bias, Out, oscale, omode, bid);
}

// ---------------- out-projection GEMM: 2-phase double-buffered, fp32 output ----------------
__global__ __launch_bounds__(256) void gemm_out(const short* __restrict__ A,
                                                const short* __restrict__ Wb,
                                                const float* __restrict__ bias,
                                                float* __restrict__ Out) {
    int mt = blockIdx.x & 63;
    int nt = blockIdx.x >> 6;
    int m0 = mt * 128, n0 = nt * 128;
    int tid = threadIdx.x;
    int w = tid >> 6, l = tid & 63, g = l >> 4, r = l & 15;
    int wm = w >> 1, wn = w & 1;

    __shared__ short As[2][128 * 32];
    __shared__ short Bs[2][128 * 32];

    int c0 = w, c1 = w + 4;
    int o0 = c0 * 1024 + l * 16, o1 = c1 * 1024 + l * 16;
    int row0 = o0 >> 6, col0 = (o0 & 63) >> 1;
    int row1 = o1 >> 6, col1 = (o1 & 63) >> 1;

    f32x4 acc[4][4];
#pragma unroll
    for (int i = 0; i < 4; i++)
#pragma unroll
        for (int j = 0; j < 4; j++) acc[i][j] = (f32x4){0.f, 0.f, 0.f, 0.f};

    gload_lds16(A + (size_t)(m0 + row0) * HIDN + col0, &As[0][c0 * 512]);
    gload_lds16(Wb + (size_t)(n0 + row0) * HIDN + col0, &Bs[0][c0 * 512]);
    gload_lds16(A + (size_t)(m0 + row1) * HIDN + col1, &As[0][c1 * 512]);
    gload_lds16(Wb + (size_t)(n0 + row1) * HIDN + col1, &Bs[0][c1 * 512]);
    __syncthreads();

    int cur = 0;
    for (int kt = 0; kt < HIDN / 32; ++kt) {
        if (kt + 1 < HIDN / 32) {
            int nb = cur ^ 1, kc = (kt + 1) * 32;
            gload_lds16(A + (size_t)(m0 + row0) * HIDN + kc + col0, &As[nb][c0 * 512]);
            gload_lds16(Wb + (size_t)(n0 + row0) * HIDN + kc + col0, &Bs[nb][c0 * 512]);
            gload_lds16(A + (size_t)(m0 + row1) * HIDN + kc + col1, &As[nb][c1 * 512]);
            gload_lds16(Wb + (size_t)(n0 + row1) * HIDN + kc + col1, &Bs[nb][c1 * 512]);
        }
        short8 af[4], bfr[4];
#pragma unroll
        for (int i = 0; i < 4; i++)
            af[i] = *(const short8*)(&As[cur][(wm * 64 + i * 16 + r) * 32 + g * 8]);
#pragma unroll
        for (int j = 0; j < 4; j++)
            bfr[j] = *(const short8*)(&Bs[cur][(wn * 64 + j * 16 + r) * 32 + g * 8]);
        __builtin_amdgcn_s_setprio(1);
#pragma unroll
        for (int i = 0; i < 4; i++)
#pragma unroll
            for (int j = 0; j < 4; j++)
                acc[i][j] = __builtin_amdgcn_mfma_f32_16x16x32_bf16(af[i], bfr[j], acc[i][j], 0, 0, 0);
        __builtin_amdgcn_s_setprio(0);
        __syncthreads();
        cur ^= 1;
    }

#pragma unroll
    for (int j = 0; j < 4; j++) {
        int n_g = n0 + wn * 64 + j * 16 + r;
        float bv = bias[n_g];
#pragma unroll
        for (int i = 0; i < 4; i++) {
#pragma unroll
            for (int rr = 0; rr < 4; rr++) {
                int m_g = m0 + wm * 64 + i * 16 + g * 4 + rr;
                Out[(size_t)m_g * HIDN + n_g] = acc[i][j][rr] + bv;
            }
        }
    }
}

// ---------------- flash attention (causal), swapped-QK^T 32x32, paired q-tiles, XCD-local ----------------
// grid = 512; bh = ((bid>>3)&7)*8 + (bid&7) keeps each bh's 8 pair-blocks on one XCD.
// Blocks run q-tiles {j, 15-j}: 36 uniform stage-iters, all finish together.
// Un-normalized exp2 softmax (no running max): |logits| <~ 10 binades, fp32/bf16 safe.
__global__ __launch_bounds__(256) void attn_kernel(const short* __restrict__ Qh,
                                                   const short* __restrict__ Kh,
                                                   const short* __restrict__ VhT,
                                                   short* __restrict__ ctx) {
    int bid = blockIdx.x;
    int j = bid >> 6;
    int bh = ((bid >> 3) & 7) * 8 + (bid & 7);
    int tid = threadIdx.x;
    int w = tid >> 6, l = tid & 63;
    int ql = l & 31, hi = l >> 5;

    __shared__ short KV[2][2][64 * 64];  // [buf][K/V][row*64 + swizzled col] = 32 KB

    const short* Qb = Qh + (size_t)bh * (S_LEN * DHEAD);
    const short* Kb = Kh + (size_t)bh * (S_LEN * DHEAD);
    const short* Vb = VhT + (size_t)bh * (DHEAD * S_LEN);

    int srow0 = tid >> 3, srow1 = srow0 + 32;
    int scol = (tid & 7) * 8;  // shorts
    int wo0 = srow0 * 64 + (scol ^ ((srow0 & 7) << 3));
    int wo1 = srow1 * 64 + (scol ^ ((srow1 & 7) << 3));

    int r0 = ql, r1 = 32 + ql;
    int sw = (ql & 7) << 3;
    int ch = hi * 8;

    int b = bh >> 4, h = bh & 15;

    for (int half = 0; half < 2; ++half) {
        int qt = half ? (15 - j) : j;
        int q_g = qt * 128 + w * 32 + ql;
        const short* qp = Qb + (size_t)q_g * DHEAD + hi * 8;
        short8 qf0 = *(const short8*)(qp);
        short8 qf1 = *(const short8*)(qp + 16);
        short8 qf2 = *(const short8*)(qp + 32);
        short8 qf3 = *(const short8*)(qp + 48);

        f32x16 accA, accB;
#pragma unroll
        for (int i = 0; i < 16; ++i) { accA[i] = 0.f; accB[i] = 0.f; }
        float lrun = 0.f;

        int ktp = (qt * 128 + w * 32) >> 6;
        int nt = 2 * qt + 2;

        __syncthreads();
        {
            short8 k0 = *(const short8*)(Kb + srow0 * 64 + scol);
            short8 k1 = *(const short8*)(Kb + srow1 * 64 + scol);
            short8 v0 = *(const short8*)(Vb + (size_t)srow0 * S_LEN + scol);
            short8 v1 = *(const short8*)(Vb + (size_t)srow1 * S_LEN + scol);
            *(short8*)(&KV[0][0][wo0]) = k0;
            *(short8*)(&KV[0][0][wo1]) = k1;
            *(short8*)(&KV[0][1][wo0]) = v0;
            *(short8*)(&KV[0][1][wo1]) = v1;
        }

        for (int kt = 0; kt < nt; ++kt) {
            __syncthreads();
            int cur = kt & 1;
            short8 pk0, pk1, pv0, pv1;
            bool pf = (kt + 1 < nt);
            if (pf) {
                const short* Kt = Kb + (kt + 1) * (64 * DHEAD);
                const short* Vt = Vb + (kt + 1) * 64;
                pk0 = *(const short8*)(Kt + srow0 * 64 + scol);
                pk1 = *(const short8*)(Kt + srow1 * 64 + scol);
                pv0 = *(const short8*)(Vt + (size_t)srow0 * S_LEN + scol);
                pv1 = *(const short8*)(Vt + (size_t)srow1 * S_LEN + scol);
            }
            if (kt <= ktp) {
                const short* Ksb = &KV[cur][0][0];
                const short* Vsb = &KV[cur][1][0];
                f32x16 st0, st1;
#pragma unroll
                for (int i = 0; i < 16; ++i) { st0[i] = 0.f; st1[i] = 0.f; }
                {
                    short8 kA, kB;
                    kA = *(const short8*)(Ksb + r0 * 64 + ((0 + ch) ^ sw));
                    kB = *(const short8*)(Ksb + r1 * 64 + ((0 + ch) ^ sw));
                    __builtin_amdgcn_s_setprio(1);
                    st0 = __builtin_amdgcn_mfma_f32_32x32x16_bf16(kA, qf0, st0, 0, 0, 0);
                    st1 = __builtin_amdgcn_mfma_f32_32x32x16_bf16(kB, qf0, st1, 0, 0, 0);
                    __builtin_amdgcn_s_setprio(0);
                    kA = *(const short8*)(Ksb + r0 * 64 + ((16 + ch) ^ sw));
                    kB = *(const short8*)(Ksb + r1 * 64 + ((16 + ch) ^ sw));
                    __builtin_amdgcn_s_setprio(1);
                    st0 = __builtin_amdgcn_mfma_f32_32x32x16_bf16(kA, qf1, st0, 0, 0, 0);
                    st1 = __builtin_amdgcn_mfma_f32_32x32x16_bf16(kB, qf1, st1, 0, 0, 0);
                    __builtin_amdgcn_s_setprio(0);
                    kA = *(const short8*)(Ksb + r0 * 64 + ((32 + ch) ^ sw));
                    kB = *(const short8*)(Ksb + r1 * 64 + ((32 + ch) ^ sw));
                    __builtin_amdgcn_s_setprio(1);
                    st0 = __builtin_amdgcn_mfma_f32_32x32x16_bf16(kA, qf2, st0, 0, 0, 0);
                    st1 = __builtin_amdgcn_mfma_f32_32x32x16_bf16(kB, qf2, st1, 0, 0, 0);
                    __builtin_amdgcn_s_setprio(0);
                    kA = *(const short8*)(Ksb + r0 * 64 + ((48 + ch) ^ sw));
                    kB = *(const short8*)(Ksb + r1 * 64 + ((48 + ch) ^ sw));
                    __builtin_amdgcn_s_setprio(1);
                    st0 = __builtin_amdgcn_mfma_f32_32x32x16_bf16(kA, qf3, st0, 0, 0, 0);
                    st1 = __builtin_amdgcn_mfma_f32_32x32x16_bf16(kB, qf3, st1, 0, 0, 0);
                    __builtin_amdgcn_s_setprio(0);
                }
                float p[32];
#pragma unroll
                for (int i = 0; i < 16; ++i) { p[i] = st0[i]; p[16 + i] = st1[i]; }
                if (kt == ktp) {
#pragma unroll
                    for (int i = 0; i < 32; ++i) {
                        int kl = (i & 3) + 8 * ((i >> 2) & 3) + 32 * (i >> 4) + 4 * hi;
                        if (kt * 64 + kl > q_g) p[i] = -1e30f;
                    }
                }
#pragma unroll
                for (int i = 0; i < 32; ++i) p[i] = exp2f(p[i]);
                float t[16];
#pragma unroll
                for (int i = 0; i < 16; ++i) t[i] = p[i] + p[i + 16];
#pragma unroll
                for (int i = 0; i < 8; ++i) t[i] = t[i] + t[i + 8];
#pragma unroll
                for (int i = 0; i < 4; ++i) t[i] = t[i] + t[i + 4];
                float rs = (t[0] + t[1]) + (t[2] + t[3]);
                rs += __shfl_xor(rs, 32);
                lrun += rs;
                {
                    unsigned u0 = cvtpk(p[0], p[1]);
                    unsigned u1 = cvtpk(p[2], p[3]);
                    unsigned u2 = cvtpk(p[4], p[5]);
                    unsigned u3 = cvtpk(p[6], p[7]);
                    plswap(u0, u2);
                    plswap(u1, u3);
                    short8 pfA = mk8(u0, u1, u2, u3);
                    unsigned u4 = cvtpk(p[8], p[9]);
                    unsigned u5 = cvtpk(p[10], p[11]);
                    unsigned u6 = cvtpk(p[12], p[13]);
                    unsigned u7 = cvtpk(p[14], p[15]);
                    plswap(u4, u6);
                    plswap(u5, u7);
                    short8 pfB = mk8(u4, u5, u6, u7);
                    short8 vA0 = *(const short8*)(Vsb + r0 * 64 + ((0 + ch) ^ sw));
                    short8 vB0 = *(const short8*)(Vsb + r1 * 64 + ((0 + ch) ^ sw));
                    short8 vA1 = *(const short8*)(Vsb + r0 * 64 + ((16 + ch) ^ sw));
                    short8 vB1 = *(const short8*)(Vsb + r1 * 64 + ((16 + ch) ^ sw));
                    __builtin_amdgcn_s_setprio(1);
                    accA = __builtin_amdgcn_mfma_f32_32x32x16_bf16(vA0, pfA, accA, 0, 0, 0);
                    accB = __builtin_amdgcn_mfma_f32_32x32x16_bf16(vB0, pfA, accB, 0, 0, 0);
                    accA = __builtin_amdgcn_mfma_f32_32x32x16_bf16(vA1, pfB, accA, 0, 0, 0);
                    accB = __builtin_amdgcn_mfma_f32_32x32x16_bf16(vB1, pfB, accB, 0, 0, 0);
                    __builtin_amdgcn_s_setprio(0);
                }
                {
                    unsigned u0 = cvtpk(p[16], p[17]);
                    unsigned u1 = cvtpk(p[18], p[19]);
                    unsigned u2 = cvtpk(p[20], p[21]);
                    unsigned u3 = cvtpk(p[22], p[23]);
                    plswap(u0, u2);
                    plswap(u1, u3);
                    short8 pfC = mk8(u0, u1, u2, u3);
                    unsigned u4 = cvtpk(p[24], p[25]);
                    unsigned u5 = cvtpk(p[26], p[27]);
                    unsigned u6 = cvtpk(p[28], p[29]);
                    unsigned u7 = cvtpk(p[30], p[31]);
                    plswap(u4, u6);
                    plswap(u5, u7);
                    short8 pfD = mk8(u4, u5, u6, u7);
                    short8 vA2 = *(const short8*)(Vsb + r0 * 64 + ((32 + ch) ^ sw));
                    short8 vB2 = *(const short8*)(Vsb + r1 * 64 + ((32 + ch) ^ sw));
                    short8 vA3 = *(const short8*)(Vsb + r0 * 64 + ((48 + ch) ^ sw));
                    short8 vB3 = *(const short8*)(Vsb + r1 * 64 + ((48 + ch) ^ sw));
                    __builtin_amdgcn_s_setprio(1);
                    accA = __builtin_amdgcn_mfma_f32_32x32x16_bf16(vA2, pfC, accA, 0, 0, 0);
                    accB = __builtin_amdgcn_mfma_f32_32x32x16_bf16(vB2, pfC, accB, 0, 0, 0);
                    accA = __builtin_amdgcn_mfma_f32_32x32x16_bf16(vA3, pfD, accA, 0, 0, 0);
                    accB = __builtin_amdgcn_mfma_f32_32x32x16_bf16(vB3, pfD, accB, 0, 0, 0);
                    __builtin_amdgcn_s_setprio(0);
                }
            }
            if (pf) {
                int nb = (kt + 1) & 1;
                *(short8*)(&KV[nb][0][wo0]) = pk0;
                *(short8*)(&KV[nb][0][wo1]) = pk1;
                *(short8*)(&KV[nb][1][wo0]) = pv0;
                *(short8*)(&KV[nb][1][wo1]) = pv1;
            }
        }

        float inv = 1.0f / lrun;
        short* cb = ctx + ((size_t)(b * S_LEN + q_g)) * HIDN + h * DHEAD;
#pragma unroll
        for (int i = 0; i < 16; ++i) {
            int d0 = (i & 3) + 8 * (i >> 2) + 4 * hi;
            cb[d0] = f2bf(accA[i] * inv);
            cb[32 + d0] = f2bf(accB[i] * inv);
        }
    }
}

extern "C" void kernel_launch(void* const* d_in, const int* in_sizes, int n_in,
                              void* d_out, int out_size, void* d_ws, size_t ws_size,
                              hipStream_t stream) {
    const float* q  = (const float*)d_in[0];
    const float* k  = (const float*)d_in[1];
    const float* v  = (const float*)d_in[2];
    // d_in[3] = attn_mask: structurally causal, not read.
    const float* Wq = (const float*)d_in[4];
    const float* bq = (const float*)d_in[5];
    const float* Wk = (const float*)d_in[6];
    const float* bk = (const float*)d_in[7];
    const float* Wv = (const float*)d_in[8];
    const float* bv = (const float*)d_in[9];
    const float* Wo = (const float*)d_in[10];
    const float* bo = (const float*)d_in[11];

    char* ws = (char*)d_ws;
    const size_t ACT = (size_t)8192 * 1024 * 2;   // 16 MB per bf16 activation
    const size_t WSZ = (size_t)1024 * 1024 * 2;   // 2 MB per bf16 weight
    short* Qh  = (short*)(ws);
    short* Kh  = (short*)(ws + ACT);
    short* VhT = (short*)(ws + 2 * ACT);
    short* qb  = (short*)(ws + 3 * ACT);          // bf16 activations for QKV GEMMs
    short* kb  = (short*)(ws + 4 * ACT);
    short* vb  = (short*)(ws + 5 * ACT);
    short* ctx = qb;                               // alias: qb dead after gemm_qkv
    short* Wqb = (short*)(ws + 6 * ACT);
    short* Wkb = (short*)(ws + 6 * ACT + WSZ);
    short* Wvb = (short*)(ws + 6 * ACT + 2 * WSZ);
    short* Wob = (short*)(ws + 6 * ACT + 3 * WSZ);
    // peak ws use: 6*16 + 8 = 104 MB

    cvt_all<<<14336, 256, 0, stream>>>(q, k, v, Wq, Wk, Wv, Wo,
                                       qb, kb, vb, Wqb, Wkb, Wvb, Wob);

    // Q pre-scaled by (1/sqrt(D)) * log2(e) so attention runs in exp2 domain.
    const float QSCALE = 0.125f * 1.44269504088896340736f;
    gemm_qkv<<<1536, 256, 0, stream>>>(qb, kb, vb, Wqb, Wkb, Wvb, bq, bk, bv,
                                       Qh, Kh, VhT, QSCALE);

    attn_kernel<<<512, 256, 0, stream>>>(Qh, Kh, VhT, ctx);

    gemm_out<<<512, 256, 0, stream>>>(ctx, Wob, bo, (float*)d_out);
}

// Round 13
// 199.978 us; speedup vs baseline: 1.0964x; 1.0964x over previous
//
#include <hip/hip_runtime.h>

typedef __attribute__((ext_vector_type(8))) short short8;
typedef __attribute__((ext_vector_type(4))) float f32x4;
typedef __attribute__((ext_vector_type(16))) float f32x16;

#define S_LEN 2048
#define HIDN  1024
#define NHEAD 16
#define DHEAD 64

__device__ __forceinline__ short f2bf(float x) {
    unsigned u = __float_as_uint(x);
    u += 0x7fffu + ((u >> 16) & 1u);
    return (short)(u >> 16);
}

typedef const __attribute__((address_space(1))) void* gas_ptr;
typedef __attribute__((address_space(3))) void* las_ptr;

__device__ __forceinline__ void gload_lds16(const void* g, void* l) {
    __builtin_amdgcn_global_load_lds((gas_ptr)g, (las_ptr)l, 16, 0, 0);
}

__device__ __forceinline__ unsigned cvtpk(float lo, float hi_) {
    unsigned r;
    asm("v_cvt_pk_bf16_f32 %0, %1, %2" : "=v"(r) : "v"(lo), "v"(hi_));
    return r;
}

__device__ __forceinline__ void plswap(unsigned& x, unsigned& y) {
    asm("v_permlane32_swap_b32 %0, %1" : "+&v"(x), "+&v"(y));
}

__device__ __forceinline__ short8 mk8(unsigned a, unsigned b, unsigned c, unsigned d) {
    union { unsigned u[4]; short8 s; } t;
    t.u[0] = a; t.u[1] = b; t.u[2] = c; t.u[3] = d;
    return t.s;
}

// ---------------- fp32 -> bf16. Weights FIRST, activations LAST (L3-warm for gemm_qkv) ----------------
__global__ __launch_bounds__(256) void cvt_all(const float* __restrict__ q,
                                               const float* __restrict__ k,
                                               const float* __restrict__ v,
                                               const float* __restrict__ Wq,
                                               const float* __restrict__ Wk,
                                               const float* __restrict__ Wv,
                                               const float* __restrict__ Wo,
                                               short* __restrict__ qb,
                                               short* __restrict__ kb,
                                               short* __restrict__ vb,
                                               short* __restrict__ wqb,
                                               short* __restrict__ wkb,
                                               short* __restrict__ wvb,
                                               short* __restrict__ wob) {
    int bid = blockIdx.x;
    const float* in;
    short* out;
    int base;
    if (bid < 2048) {
        int wsel = bid >> 9;
        base = bid & 511;
        in  = wsel == 0 ? Wq  : wsel == 1 ? Wk  : wsel == 2 ? Wv  : Wo;
        out = wsel == 0 ? wqb : wsel == 1 ? wkb : wsel == 2 ? wvb : wob;
    } else if (bid < 6144)  { in = q; out = qb; base = bid - 2048; }
    else if (bid < 10240)   { in = k; out = kb; base = bid - 6144; }
    else                    { in = v; out = vb; base = bid - 10240; }
    int i = (base * 256 + threadIdx.x) * 8;
    float4 a = *(const float4*)(in + i);
    float4 b = *(const float4*)(in + i + 4);
    short8 o;
    o[0] = f2bf(a.x); o[1] = f2bf(a.y); o[2] = f2bf(a.z); o[3] = f2bf(a.w);
    o[4] = f2bf(b.x); o[5] = f2bf(b.y); o[6] = f2bf(b.z); o[7] = f2bf(b.w);
    *(short8*)(out + i) = o;
}

// ---------------- GEMM core: bf16 x bf16, BK=64 single-buffer, XOR-swizzled LDS ----------------
// 16 K-steps (vs 32 at BK=32) -> half the barrier drains. Rows are 128B so the tile is
// XOR-swizzled: linear gload_lds dest + pre-swizzled SOURCE slot (l&7)^(l>>3), ds_read
// applies ^(r&7) -> 2-way banks (free). Same addressing proven correct in R11's A path.
__device__ __forceinline__ void gemm_k64(const short* A, const short* Wb,
                                         short* As, short* Bs, f32x4 acc[4][4],
                                         int m0, int n0) {
    int tid = threadIdx.x;
    int w = tid >> 6, l = tid & 63, g = l >> 4, r = l & 15;
    int wm = w >> 1, wn = w & 1;
    int r7 = r & 7;

    int rowin = l >> 3;                       // 0..7 within 8-row chunk group
    int scol = ((l & 7) ^ rowin) * 8;         // pre-swizzled source col (shorts)
    int dst = l * 8;                          // + chunk*512

    for (int kt = 0; kt < HIDN / 64; ++kt) {
        __syncthreads();
#pragma unroll
        for (int i = 0; i < 4; i++) {
            int c = w * 4 + i;
            int row = c * 8 + rowin;
            gload_lds16(A + (size_t)(m0 + row) * HIDN + kt * 64 + scol, As + c * 512 + dst);
            gload_lds16(Wb + (size_t)(n0 + row) * HIDN + kt * 64 + scol, Bs + c * 512 + dst);
        }
        __syncthreads();

        short8 af[4][2], bfr[4][2];
#pragma unroll
        for (int i = 0; i < 4; i++)
#pragma unroll
            for (int ks = 0; ks < 2; ks++)
                af[i][ks] = *(const short8*)(As + (wm * 64 + i * 16 + r) * 64 +
                                             ((((ks << 2) + g) ^ r7) << 3));
#pragma unroll
        for (int j = 0; j < 4; j++)
#pragma unroll
            for (int ks = 0; ks < 2; ks++)
                bfr[j][ks] = *(const short8*)(Bs + (wn * 64 + j * 16 + r) * 64 +
                                              ((((ks << 2) + g) ^ r7) << 3));
        __builtin_amdgcn_s_setprio(1);
#pragma unroll
        for (int i = 0; i < 4; i++)
#pragma unroll
            for (int j = 0; j < 4; j++) {
                acc[i][j] = __builtin_amdgcn_mfma_f32_16x16x32_bf16(af[i][0], bfr[j][0], acc[i][j], 0, 0, 0);
                acc[i][j] = __builtin_amdgcn_mfma_f32_16x16x32_bf16(af[i][1], bfr[j][1], acc[i][j], 0, 0, 0);
            }
        __builtin_amdgcn_s_setprio(0);
    }
}

__global__ __launch_bounds__(256) void gemm_qkv(const short* __restrict__ qb,
                                                const short* __restrict__ kb,
                                                const short* __restrict__ vb,
                                                const short* __restrict__ Wqb,
                                                const short* __restrict__ Wkb,
                                                const short* __restrict__ Wvb,
                                                const float* __restrict__ bq,
                                                const float* __restrict__ bk,
                                                const float* __restrict__ bv,
                                                short* __restrict__ Qh,
                                                short* __restrict__ Kh,
                                                short* __restrict__ VhT,
                                                float qscale) {
    int which = blockIdx.x >> 9;
    int bid = blockIdx.x & 511;
    const short* A = which == 0 ? qb : which == 1 ? kb : vb;
    const short* Wb = which == 0 ? Wqb : which == 1 ? Wkb : Wvb;
    const float* bias = which == 0 ? bq : which == 1 ? bk : bv;
    short* Out = which == 0 ? Qh : which == 1 ? Kh : VhT;
    float oscale = which == 0 ? qscale : 1.0f;
    int omode = which == 2 ? 1 : 0;

    int mt = bid & 63, nt = bid >> 6;
    int m0 = mt * 128, n0 = nt * 128;
    int tid = threadIdx.x;
    int w = tid >> 6, l = tid & 63, g = l >> 4, r = l & 15;
    int wm = w >> 1, wn = w & 1;

    __shared__ short As[128 * 64];
    __shared__ short Bs[128 * 64];

    f32x4 acc[4][4];
#pragma unroll
    for (int i = 0; i < 4; i++)
#pragma unroll
        for (int j = 0; j < 4; j++) acc[i][j] = (f32x4){0.f, 0.f, 0.f, 0.f};

    gemm_k64(A, Wb, As, Bs, acc, m0, n0);

#pragma unroll
    for (int j = 0; j < 4; j++) {
        int n_g = n0 + wn * 64 + j * 16 + r;
        float bv2 = bias[n_g];
        int h = n_g >> 6, d = n_g & 63;
#pragma unroll
        for (int i = 0; i < 4; i++) {
#pragma unroll
            for (int rr = 0; rr < 4; rr++) {
                int m_g = m0 + wm * 64 + i * 16 + g * 4 + rr;
                float val = (acc[i][j][rr] + bv2) * oscale;
                int b = m_g >> 11, s = m_g & 2047;
                size_t idx = (omode == 0)
                    ? (((size_t)(b * NHEAD + h)) * S_LEN + s) * DHEAD + d
                    : (((size_t)(b * NHEAD + h)) * DHEAD + d) * S_LEN + s;
                Out[idx] = f2bf(val);
            }
        }
    }
}

__global__ __launch_bounds__(256) void gemm_out(const short* __restrict__ A,
                                                const short* __restrict__ Wb,
                                                const float* __restrict__ bias,
                                                float* __restrict__ Out) {
    int mt = blockIdx.x & 63, nt = blockIdx.x >> 6;
    int m0 = mt * 128, n0 = nt * 128;
    int tid = threadIdx.x;
    int w = tid >> 6, l = tid & 63, g = l >> 4, r = l & 15;
    int wm = w >> 1, wn = w & 1;

    __shared__ short As[128 * 64];
    __shared__ short Bs[128 * 64];

    f32x4 acc[4][4];
#pragma unroll
    for (int i = 0; i < 4; i++)
#pragma unroll
        for (int j = 0; j < 4; j++) acc[i][j] = (f32x4){0.f, 0.f, 0.f, 0.f};

    gemm_k64(A, Wb, As, Bs, acc, m0, n0);

#pragma unroll
    for (int j = 0; j < 4; j++) {
        int n_g = n0 + wn * 64 + j * 16 + r;
        float bv = bias[n_g];
#pragma unroll
        for (int i = 0; i < 4; i++) {
#pragma unroll
            for (int rr = 0; rr < 4; rr++) {
                int m_g = m0 + wm * 64 + i * 16 + g * 4 + rr;
                Out[(size_t)m_g * HIDN + n_g] = acc[i][j][rr] + bv;
            }
        }
    }
}

// ---------------- flash attention (causal), swapped-QK^T 32x32, paired q-tiles, XCD-local ----------------
// grid = 512; bh = ((bid>>3)&7)*8 + (bid&7) keeps each bh's 8 pair-blocks on one XCD.
// Blocks run q-tiles {j, 15-j}: 36 uniform stage-iters, all finish together.
// Un-normalized exp2 softmax (no running max): |logits| <~ 10 binades, fp32/bf16 safe.
__global__ __launch_bounds__(256) void attn_kernel(const short* __restrict__ Qh,
                                                   const short* __restrict__ Kh,
                                                   const short* __restrict__ VhT,
                                                   short* __restrict__ ctx) {
    int bid = blockIdx.x;
    int j = bid >> 6;
    int bh = ((bid >> 3) & 7) * 8 + (bid & 7);
    int tid = threadIdx.x;
    int w = tid >> 6, l = tid & 63;
    int ql = l & 31, hi = l >> 5;

    __shared__ short KV[2][2][64 * 64];

    const short* Qb = Qh + (size_t)bh * (S_LEN * DHEAD);
    const short* Kb = Kh + (size_t)bh * (S_LEN * DHEAD);
    const short* Vb = VhT + (size_t)bh * (DHEAD * S_LEN);

    int srow0 = tid >> 3, srow1 = srow0 + 32;
    int scol = (tid & 7) * 8;
    int wo0 = srow0 * 64 + (scol ^ ((srow0 & 7) << 3));
    int wo1 = srow1 * 64 + (scol ^ ((srow1 & 7) << 3));

    int r0 = ql, r1 = 32 + ql;
    int sw = (ql & 7) << 3;
    int ch = hi * 8;

    int b = bh >> 4, h = bh & 15;

    for (int half = 0; half < 2; ++half) {
        int qt = half ? (15 - j) : j;
        int q_g = qt * 128 + w * 32 + ql;
        const short* qp = Qb + (size_t)q_g * DHEAD + hi * 8;
        short8 qf0 = *(const short8*)(qp);
        short8 qf1 = *(const short8*)(qp + 16);
        short8 qf2 = *(const short8*)(qp + 32);
        short8 qf3 = *(const short8*)(qp + 48);

        f32x16 accA, accB;
#pragma unroll
        for (int i = 0; i < 16; ++i) { accA[i] = 0.f; accB[i] = 0.f; }
        float lrun = 0.f;

        int ktp = (qt * 128 + w * 32) >> 6;
        int nt = 2 * qt + 2;

        __syncthreads();
        {
            short8 k0 = *(const short8*)(Kb + srow0 * 64 + scol);
            short8 k1 = *(const short8*)(Kb + srow1 * 64 + scol);
            short8 v0 = *(const short8*)(Vb + (size_t)srow0 * S_LEN + scol);
            short8 v1 = *(const short8*)(Vb + (size_t)srow1 * S_LEN + scol);
            *(short8*)(&KV[0][0][wo0]) = k0;
            *(short8*)(&KV[0][0][wo1]) = k1;
            *(short8*)(&KV[0][1][wo0]) = v0;
            *(short8*)(&KV[0][1][wo1]) = v1;
        }

        for (int kt = 0; kt < nt; ++kt) {
            __syncthreads();
            int cur = kt & 1;
            short8 pk0, pk1, pv0, pv1;
            bool pf = (kt + 1 < nt);
            if (pf) {
                const short* Kt = Kb + (kt + 1) * (64 * DHEAD);
                const short* Vt = Vb + (kt + 1) * 64;
                pk0 = *(const short8*)(Kt + srow0 * 64 + scol);
                pk1 = *(const short8*)(Kt + srow1 * 64 + scol);
                pv0 = *(const short8*)(Vt + (size_t)srow0 * S_LEN + scol);
                pv1 = *(const short8*)(Vt + (size_t)srow1 * S_LEN + scol);
            }
            if (kt <= ktp) {
                const short* Ksb = &KV[cur][0][0];
                const short* Vsb = &KV[cur][1][0];
                f32x16 st0, st1;
#pragma unroll
                for (int i = 0; i < 16; ++i) { st0[i] = 0.f; st1[i] = 0.f; }
                {
                    short8 kA, kB;
                    kA = *(const short8*)(Ksb + r0 * 64 + ((0 + ch) ^ sw));
                    kB = *(const short8*)(Ksb + r1 * 64 + ((0 + ch) ^ sw));
                    __builtin_amdgcn_s_setprio(1);
                    st0 = __builtin_amdgcn_mfma_f32_32x32x16_bf16(kA, qf0, st0, 0, 0, 0);
                    st1 = __builtin_amdgcn_mfma_f32_32x32x16_bf16(kB, qf0, st1, 0, 0, 0);
                    __builtin_amdgcn_s_setprio(0);
                    kA = *(const short8*)(Ksb + r0 * 64 + ((16 + ch) ^ sw));
                    kB = *(const short8*)(Ksb + r1 * 64 + ((16 + ch) ^ sw));
                    __builtin_amdgcn_s_setprio(1);
                    st0 = __builtin_amdgcn_mfma_f32_32x32x16_bf16(kA, qf1, st0, 0, 0, 0);
                    st1 = __builtin_amdgcn_mfma_f32_32x32x16_bf16(kB, qf1, st1, 0, 0, 0);
                    __builtin_amdgcn_s_setprio(0);
                    kA = *(const short8*)(Ksb + r0 * 64 + ((32 + ch) ^ sw));
                    kB = *(const short8*)(Ksb + r1 * 64 + ((32 + ch) ^ sw));
                    __builtin_amdgcn_s_setprio(1);
                    st0 = __builtin_amdgcn_mfma_f32_32x32x16_bf16(kA, qf2, st0, 0, 0, 0);
                    st1 = __builtin_amdgcn_mfma_f32_32x32x16_bf16(kB, qf2, st1, 0, 0, 0);
                    __builtin_amdgcn_s_setprio(0);
                    kA = *(const short8*)(Ksb + r0 * 64 + ((48 + ch) ^ sw));
                    kB = *(const short8*)(Ksb + r1 * 64 + ((48 + ch) ^ sw));
                    __builtin_amdgcn_s_setprio(1);
                    st0 = __builtin_amdgcn_mfma_f32_32x32x16_bf16(kA, qf3, st0, 0, 0, 0);
                    st1 = __builtin_amdgcn_mfma_f32_32x32x16_bf16(kB, qf3, st1, 0, 0, 0);
                    __builtin_amdgcn_s_setprio(0);
                }
                float p[32];
#pragma unroll
                for (int i = 0; i < 16; ++i) { p[i] = st0[i]; p[16 + i] = st1[i]; }
                if (kt == ktp) {
#pragma unroll
                    for (int i = 0; i < 32; ++i) {
                        int kl = (i & 3) + 8 * ((i >> 2) & 3) + 32 * (i >> 4) + 4 * hi;
                        if (kt * 64 + kl > q_g) p[i] = -1e30f;
                    }
                }
#pragma unroll
                for (int i = 0; i < 32; ++i) p[i] = exp2f(p[i]);
                float t[16];
#pragma unroll
                for (int i = 0; i < 16; ++i) t[i] = p[i] + p[i + 16];
#pragma unroll
                for (int i = 0; i < 8; ++i) t[i] = t[i] + t[i + 8];
#pragma unroll
                for (int i = 0; i < 4; ++i) t[i] = t[i] + t[i + 4];
                float rs = (t[0] + t[1]) + (t[2] + t[3]);
                rs += __shfl_xor(rs, 32);
                lrun += rs;
                {
                    unsigned u0 = cvtpk(p[0], p[1]);
                    unsigned u1 = cvtpk(p[2], p[3]);
                    unsigned u2 = cvtpk(p[4], p[5]);
                    unsigned u3 = cvtpk(p[6], p[7]);
                    plswap(u0, u2);
                    plswap(u1, u3);
                    short8 pfA = mk8(u0, u1, u2, u3);
                    unsigned u4 = cvtpk(p[8], p[9]);
                    unsigned u5 = cvtpk(p[10], p[11]);
                    unsigned u6 = cvtpk(p[12], p[13]);
                    unsigned u7 = cvtpk(p[14], p[15]);
                    plswap(u4, u6);
                    plswap(u5, u7);
                    short8 pfB = mk8(u4, u5, u6, u7);
                    short8 vA0 = *(const short8*)(Vsb + r0 * 64 + ((0 + ch) ^ sw));
                    short8 vB0 = *(const short8*)(Vsb + r1 * 64 + ((0 + ch) ^ sw));
                    short8 vA1 = *(const short8*)(Vsb + r0 * 64 + ((16 + ch) ^ sw));
                    short8 vB1 = *(const short8*)(Vsb + r1 * 64 + ((16 + ch) ^ sw));
                    __builtin_amdgcn_s_setprio(1);
                    accA = __builtin_amdgcn_mfma_f32_32x32x16_bf16(vA0, pfA, accA, 0, 0, 0);
                    accB = __builtin_amdgcn_mfma_f32_32x32x16_bf16(vB0, pfA, accB, 0, 0, 0);
                    accA = __builtin_amdgcn_mfma_f32_32x32x16_bf16(vA1, pfB, accA, 0, 0, 0);
                    accB = __builtin_amdgcn_mfma_f32_32x32x16_bf16(vB1, pfB, accB, 0, 0, 0);
                    __builtin_amdgcn_s_setprio(0);
                }
                {
                    unsigned u0 = cvtpk(p[16], p[17]);
                    unsigned u1 = cvtpk(p[18], p[19]);
                    unsigned u2 = cvtpk(p[20], p[21]);
                    unsigned u3 = cvtpk(p[22], p[23]);
                    plswap(u0, u2);
                    plswap(u1, u3);
                    short8 pfC = mk8(u0, u1, u2, u3);
                    unsigned u4 = cvtpk(p[24], p[25]);
                    unsigned u5 = cvtpk(p[26], p[27]);
                    unsigned u6 = cvtpk(p[28], p[29]);
                    unsigned u7 = cvtpk(p[30], p[31]);
                    plswap(u4, u6);
                    plswap(u5, u7);
                    short8 pfD = mk8(u4, u5, u6, u7);
                    short8 vA2 = *(const short8*)(Vsb + r0 * 64 + ((32 + ch) ^ sw));
                    short8 vB2 = *(const short8*)(Vsb + r1 * 64 + ((32 + ch) ^ sw));
                    short8 vA3 = *(const short8*)(Vsb + r0 * 64 + ((48 + ch) ^ sw));
                    short8 vB3 = *(const short8*)(Vsb + r1 * 64 + ((48 + ch) ^ sw));
                    __builtin_amdgcn_s_setprio(1);
                    accA = __builtin_amdgcn_mfma_f32_32x32x16_bf16(vA2, pfC, accA, 0, 0, 0);
                    accB = __builtin_amdgcn_mfma_f32_32x32x16_bf16(vB2, pfC, accB, 0, 0, 0);
                    accA = __builtin_amdgcn_mfma_f32_32x32x16_bf16(vA3, pfD, accA, 0, 0, 0);
                    accB = __builtin_amdgcn_mfma_f32_32x32x16_bf16(vB3, pfD, accB, 0, 0, 0);
                    __builtin_amdgcn_s_setprio(0);
                }
            }
            if (pf) {
                int nb = (kt + 1) & 1;
                *(short8*)(&KV[nb][0][wo0]) = pk0;
                *(short8*)(&KV[nb][0][wo1]) = pk1;
                *(short8*)(&KV[nb][1][wo0]) = pv0;
                *(short8*)(&KV[nb][1][wo1]) = pv1;
            }
        }

        float inv = 1.0f / lrun;
        short* cb = ctx + ((size_t)(b * S_LEN + q_g)) * HIDN + h * DHEAD;
#pragma unroll
        for (int i = 0; i < 16; ++i) {
            int d0 = (i & 3) + 8 * (i >> 2) + 4 * hi;
            cb[d0] = f2bf(accA[i] * inv);
            cb[32 + d0] = f2bf(accB[i] * inv);
        }
    }
}

extern "C" void kernel_launch(void* const* d_in, const int* in_sizes, int n_in,
                              void* d_out, int out_size, void* d_ws, size_t ws_size,
                              hipStream_t stream) {
    const float* q  = (const float*)d_in[0];
    const float* k  = (const float*)d_in[1];
    const float* v  = (const float*)d_in[2];
    // d_in[3] = attn_mask: structurally causal, not read.
    const float* Wq = (const float*)d_in[4];
    const float* bq = (const float*)d_in[5];
    const float* Wk = (const float*)d_in[6];
    const float* bk = (const float*)d_in[7];
    const float* Wv = (const float*)d_in[8];
    const float* bv = (const float*)d_in[9];
    const float* Wo = (const float*)d_in[10];
    const float* bo = (const float*)d_in[11];

    char* ws = (char*)d_ws;
    const size_t ACT = (size_t)8192 * 1024 * 2;
    const size_t WSZ = (size_t)1024 * 1024 * 2;
    short* Qh  = (short*)(ws);
    short* Kh  = (short*)(ws + ACT);
    short* VhT = (short*)(ws + 2 * ACT);
    short* qb  = (short*)(ws + 3 * ACT);
    short* kb  = (short*)(ws + 4 * ACT);
    short* vb  = (short*)(ws + 5 * ACT);
    short* ctx = qb;
    short* Wqb = (short*)(ws + 6 * ACT);
    short* Wkb = (short*)(ws + 6 * ACT + WSZ);
    short* Wvb = (short*)(ws + 6 * ACT + 2 * WSZ);
    short* Wob = (short*)(ws + 6 * ACT + 3 * WSZ);

    cvt_all<<<14336, 256, 0, stream>>>(q, k, v, Wq, Wk, Wv, Wo,
                                       qb, kb, vb, Wqb, Wkb, Wvb, Wob);

    const float QSCALE = 0.125f * 1.44269504088896340736f;
    gemm_qkv<<<1536, 256, 0, stream>>>(qb, kb, vb, Wqb, Wkb, Wvb, bq, bk, bv,
                                       Qh, Kh, VhT, QSCALE);

    attn_kernel<<<512, 256, 0, stream>>>(Qh, Kh, VhT, ctx);

    gemm_out<<<512, 256, 0, stream>>>(ctx, Wob, bo, (float*)d_out);
}

// Round 14
// 199.542 us; speedup vs baseline: 1.0988x; 1.0022x over previous
//
#include <hip/hip_runtime.h>

typedef __attribute__((ext_vector_type(8))) short short8;
typedef __attribute__((ext_vector_type(4))) float f32x4;
typedef __attribute__((ext_vector_type(16))) float f32x16;

#define S_LEN 2048
#define HIDN  1024
#define NHEAD 16
#define DHEAD 64

__device__ __forceinline__ short f2bf(float x) {
    unsigned u = __float_as_uint(x);
    u += 0x7fffu + ((u >> 16) & 1u);
    return (short)(u >> 16);
}

typedef const __attribute__((address_space(1))) void* gas_ptr;
typedef __attribute__((address_space(3))) void* las_ptr;

__device__ __forceinline__ void gload_lds16(const void* g, void* l) {
    __builtin_amdgcn_global_load_lds((gas_ptr)g, (las_ptr)l, 16, 0, 0);
}

__device__ __forceinline__ unsigned cvtpk(float lo, float hi_) {
    unsigned r;
    asm("v_cvt_pk_bf16_f32 %0, %1, %2" : "=v"(r) : "v"(lo), "v"(hi_));
    return r;
}

__device__ __forceinline__ void plswap(unsigned& x, unsigned& y) {
    asm("v_permlane32_swap_b32 %0, %1" : "+&v"(x), "+&v"(y));
}

__device__ __forceinline__ short8 mk8(unsigned a, unsigned b, unsigned c, unsigned d) {
    union { unsigned u[4]; short8 s; } t;
    t.u[0] = a; t.u[1] = b; t.u[2] = c; t.u[3] = d;
    return t.s;
}

// ---------------- fp32 -> bf16. Weights FIRST, activations LAST (L3-warm for gemm_qkv) ----------------
__global__ __launch_bounds__(256) void cvt_all(const float* __restrict__ q,
                                               const float* __restrict__ k,
                                               const float* __restrict__ v,
                                               const float* __restrict__ Wq,
                                               const float* __restrict__ Wk,
                                               const float* __restrict__ Wv,
                                               const float* __restrict__ Wo,
                                               short* __restrict__ qb,
                                               short* __restrict__ kb,
                                               short* __restrict__ vb,
                                               short* __restrict__ wqb,
                                               short* __restrict__ wkb,
                                               short* __restrict__ wvb,
                                               short* __restrict__ wob) {
    int bid = blockIdx.x;
    const float* in;
    short* out;
    int base;
    if (bid < 2048) {
        int wsel = bid >> 9;
        base = bid & 511;
        in  = wsel == 0 ? Wq  : wsel == 1 ? Wk  : wsel == 2 ? Wv  : Wo;
        out = wsel == 0 ? wqb : wsel == 1 ? wkb : wsel == 2 ? wvb : wob;
    } else if (bid < 6144)  { in = q; out = qb; base = bid - 2048; }
    else if (bid < 10240)   { in = k; out = kb; base = bid - 6144; }
    else                    { in = v; out = vb; base = bid - 10240; }
    int i = (base * 256 + threadIdx.x) * 8;
    float4 a = *(const float4*)(in + i);
    float4 b = *(const float4*)(in + i + 4);
    short8 o;
    o[0] = f2bf(a.x); o[1] = f2bf(a.y); o[2] = f2bf(a.z); o[3] = f2bf(a.w);
    o[4] = f2bf(b.x); o[5] = f2bf(b.y); o[6] = f2bf(b.z); o[7] = f2bf(b.w);
    *(short8*)(out + i) = o;
}

// ---------------- GEMM core: bf16 x bf16, BK=64, double-buffered, XOR-swizzled, T3-minimum ----------------
// Per iter: STAGE(buf^1, kt+1) -> ds_read(buf)+MFMA -> __syncthreads (single barrier;
// its vmcnt(0) lands AFTER the full 32-MFMA block, so the just-issued loads are mostly
// landed). Swizzle: linear gload_lds dest + pre-swizzled source slot (l&7)^(l>>3), read
// ^(r&7) -> conflict-free (R13: SQ_LDS_BANK_CONFLICT == 0).
// Hazards: RAW -> buf staged kt-1, drained by kt-1's barrier. WAR -> buf^1 readers
// lgkm-complete before kt-1's barrier. LDS 64KB -> 2 blocks/CU.
__device__ __forceinline__ void gemm_k64_db(const short* A, const short* Wb,
                                            short* As0, short* As1,
                                            short* Bs0, short* Bs1,
                                            f32x4 acc[4][4], int m0, int n0) {
    int tid = threadIdx.x;
    int w = tid >> 6, l = tid & 63, g = l >> 4, r = l & 15;
    int wm = w >> 1, wn = w & 1;
    int r7 = r & 7;

    int rowin = l >> 3;
    int scol = ((l & 7) ^ rowin) * 8;   // pre-swizzled source col (shorts)
    int dst = l * 8;

    // prologue: stage tile 0 into buf 0
#pragma unroll
    for (int i = 0; i < 4; i++) {
        int c = w * 4 + i;
        int row = c * 8 + rowin;
        gload_lds16(A + (size_t)(m0 + row) * HIDN + scol, As0 + c * 512 + dst);
        gload_lds16(Wb + (size_t)(n0 + row) * HIDN + scol, Bs0 + c * 512 + dst);
    }
    __syncthreads();

    for (int kt = 0; kt < HIDN / 64; ++kt) {
        short* Asc = (kt & 1) ? As1 : As0;
        short* Bsc = (kt & 1) ? Bs1 : Bs0;
        short* Asn = (kt & 1) ? As0 : As1;
        short* Bsn = (kt & 1) ? Bs0 : Bs1;
        if (kt + 1 < HIDN / 64) {   // prefetch next tile; flies during this MFMA block
            int kc = (kt + 1) * 64;
#pragma unroll
            for (int i = 0; i < 4; i++) {
                int c = w * 4 + i;
                int row = c * 8 + rowin;
                gload_lds16(A + (size_t)(m0 + row) * HIDN + kc + scol, Asn + c * 512 + dst);
                gload_lds16(Wb + (size_t)(n0 + row) * HIDN + kc + scol, Bsn + c * 512 + dst);
            }
        }
        short8 af[4][2], bfr[4][2];
#pragma unroll
        for (int i = 0; i < 4; i++)
#pragma unroll
            for (int ks = 0; ks < 2; ks++)
                af[i][ks] = *(const short8*)(Asc + (wm * 64 + i * 16 + r) * 64 +
                                             ((((ks << 2) + g) ^ r7) << 3));
#pragma unroll
        for (int j = 0; j < 4; j++)
#pragma unroll
            for (int ks = 0; ks < 2; ks++)
                bfr[j][ks] = *(const short8*)(Bsc + (wn * 64 + j * 16 + r) * 64 +
                                              ((((ks << 2) + g) ^ r7) << 3));
        __builtin_amdgcn_s_setprio(1);
#pragma unroll
        for (int i = 0; i < 4; i++)
#pragma unroll
            for (int j = 0; j < 4; j++) {
                acc[i][j] = __builtin_amdgcn_mfma_f32_16x16x32_bf16(af[i][0], bfr[j][0], acc[i][j], 0, 0, 0);
                acc[i][j] = __builtin_amdgcn_mfma_f32_16x16x32_bf16(af[i][1], bfr[j][1], acc[i][j], 0, 0, 0);
            }
        __builtin_amdgcn_s_setprio(0);
        __syncthreads();   // single barrier/iter: drains this iter's prefetch (mostly landed)
    }
}

__global__ __launch_bounds__(256) void gemm_qkv(const short* __restrict__ qb,
                                                const short* __restrict__ kb,
                                                const short* __restrict__ vb,
                                                const short* __restrict__ Wqb,
                                                const short* __restrict__ Wkb,
                                                const short* __restrict__ Wvb,
                                                const float* __restrict__ bq,
                                                const float* __restrict__ bk,
                                                const float* __restrict__ bv,
                                                short* __restrict__ Qh,
                                                short* __restrict__ Kh,
                                                short* __restrict__ VhT,
                                                float qscale) {
    int which = blockIdx.x >> 9;
    int bid = blockIdx.x & 511;
    const short* A = which == 0 ? qb : which == 1 ? kb : vb;
    const short* Wb = which == 0 ? Wqb : which == 1 ? Wkb : Wvb;
    const float* bias = which == 0 ? bq : which == 1 ? bk : bv;
    short* Out = which == 0 ? Qh : which == 1 ? Kh : VhT;
    float oscale = which == 0 ? qscale : 1.0f;
    int omode = which == 2 ? 1 : 0;

    int mt = bid & 63, nt = bid >> 6;
    int m0 = mt * 128, n0 = nt * 128;
    int tid = threadIdx.x;
    int w = tid >> 6, l = tid & 63, g = l >> 4, r = l & 15;
    int wm = w >> 1, wn = w & 1;

    __shared__ short As0[128 * 64], As1[128 * 64];
    __shared__ short Bs0[128 * 64], Bs1[128 * 64];   // 64 KB total

    f32x4 acc[4][4];
#pragma unroll
    for (int i = 0; i < 4; i++)
#pragma unroll
        for (int j = 0; j < 4; j++) acc[i][j] = (f32x4){0.f, 0.f, 0.f, 0.f};

    gemm_k64_db(A, Wb, As0, As1, Bs0, Bs1, acc, m0, n0);

#pragma unroll
    for (int j = 0; j < 4; j++) {
        int n_g = n0 + wn * 64 + j * 16 + r;
        float bv2 = bias[n_g];
        int h = n_g >> 6, d = n_g & 63;
#pragma unroll
        for (int i = 0; i < 4; i++) {
#pragma unroll
            for (int rr = 0; rr < 4; rr++) {
                int m_g = m0 + wm * 64 + i * 16 + g * 4 + rr;
                float val = (acc[i][j][rr] + bv2) * oscale;
                int b = m_g >> 11, s = m_g & 2047;
                size_t idx = (omode == 0)
                    ? (((size_t)(b * NHEAD + h)) * S_LEN + s) * DHEAD + d
                    : (((size_t)(b * NHEAD + h)) * DHEAD + d) * S_LEN + s;
                Out[idx] = f2bf(val);
            }
        }
    }
}

__global__ __launch_bounds__(256) void gemm_out(const short* __restrict__ A,
                                                const short* __restrict__ Wb,
                                                const float* __restrict__ bias,
                                                float* __restrict__ Out) {
    int mt = blockIdx.x & 63, nt = blockIdx.x >> 6;
    int m0 = mt * 128, n0 = nt * 128;
    int tid = threadIdx.x;
    int w = tid >> 6, l = tid & 63, g = l >> 4, r = l & 15;
    int wm = w >> 1, wn = w & 1;

    __shared__ short As0[128 * 64], As1[128 * 64];
    __shared__ short Bs0[128 * 64], Bs1[128 * 64];

    f32x4 acc[4][4];
#pragma unroll
    for (int i = 0; i < 4; i++)
#pragma unroll
        for (int j = 0; j < 4; j++) acc[i][j] = (f32x4){0.f, 0.f, 0.f, 0.f};

    gemm_k64_db(A, Wb, As0, As1, Bs0, Bs1, acc, m0, n0);

#pragma unroll
    for (int j = 0; j < 4; j++) {
        int n_g = n0 + wn * 64 + j * 16 + r;
        float bv = bias[n_g];
#pragma unroll
        for (int i = 0; i < 4; i++) {
#pragma unroll
            for (int rr = 0; rr < 4; rr++) {
                int m_g = m0 + wm * 64 + i * 16 + g * 4 + rr;
                Out[(size_t)m_g * HIDN + n_g] = acc[i][j][rr] + bv;
            }
        }
    }
}

// ---------------- flash attention (causal), swapped-QK^T 32x32, paired q-tiles, XCD-local ----------------
// grid = 512; bh = ((bid>>3)&7)*8 + (bid&7) keeps each bh's 8 pair-blocks on one XCD.
// Blocks run q-tiles {j, 15-j}: 36 uniform stage-iters, all finish together.
// Un-normalized exp2 softmax (no running max): |logits| <~ 10 binades, fp32/bf16 safe.
__global__ __launch_bounds__(256) void attn_kernel(const short* __restrict__ Qh,
                                                   const short* __restrict__ Kh,
                                                   const short* __restrict__ VhT,
                                                   short* __restrict__ ctx) {
    int bid = blockIdx.x;
    int j = bid >> 6;
    int bh = ((bid >> 3) & 7) * 8 + (bid & 7);
    int tid = threadIdx.x;
    int w = tid >> 6, l = tid & 63;
    int ql = l & 31, hi = l >> 5;

    __shared__ short KV[2][2][64 * 64];

    const short* Qb = Qh + (size_t)bh * (S_LEN * DHEAD);
    const short* Kb = Kh + (size_t)bh * (S_LEN * DHEAD);
    const short* Vb = VhT + (size_t)bh * (DHEAD * S_LEN);

    int srow0 = tid >> 3, srow1 = srow0 + 32;
    int scol = (tid & 7) * 8;
    int wo0 = srow0 * 64 + (scol ^ ((srow0 & 7) << 3));
    int wo1 = srow1 * 64 + (scol ^ ((srow1 & 7) << 3));

    int r0 = ql, r1 = 32 + ql;
    int sw = (ql & 7) << 3;
    int ch = hi * 8;

    int b = bh >> 4, h = bh & 15;

    for (int half = 0; half < 2; ++half) {
        int qt = half ? (15 - j) : j;
        int q_g = qt * 128 + w * 32 + ql;
        const short* qp = Qb + (size_t)q_g * DHEAD + hi * 8;
        short8 qf0 = *(const short8*)(qp);
        short8 qf1 = *(const short8*)(qp + 16);
        short8 qf2 = *(const short8*)(qp + 32);
        short8 qf3 = *(const short8*)(qp + 48);

        f32x16 accA, accB;
#pragma unroll
        for (int i = 0; i < 16; ++i) { accA[i] = 0.f; accB[i] = 0.f; }
        float lrun = 0.f;

        int ktp = (qt * 128 + w * 32) >> 6;
        int nt = 2 * qt + 2;

        __syncthreads();
        {
            short8 k0 = *(const short8*)(Kb + srow0 * 64 + scol);
            short8 k1 = *(const short8*)(Kb + srow1 * 64 + scol);
            short8 v0 = *(const short8*)(Vb + (size_t)srow0 * S_LEN + scol);
            short8 v1 = *(const short8*)(Vb + (size_t)srow1 * S_LEN + scol);
            *(short8*)(&KV[0][0][wo0]) = k0;
            *(short8*)(&KV[0][0][wo1]) = k1;
            *(short8*)(&KV[0][1][wo0]) = v0;
            *(short8*)(&KV[0][1][wo1]) = v1;
        }

        for (int kt = 0; kt < nt; ++kt) {
            __syncthreads();
            int cur = kt & 1;
            short8 pk0, pk1, pv0, pv1;
            bool pf = (kt + 1 < nt);
            if (pf) {
                const short* Kt = Kb + (kt + 1) * (64 * DHEAD);
                const short* Vt = Vb + (kt + 1) * 64;
                pk0 = *(const short8*)(Kt + srow0 * 64 + scol);
                pk1 = *(const short8*)(Kt + srow1 * 64 + scol);
                pv0 = *(const short8*)(Vt + (size_t)srow0 * S_LEN + scol);
                pv1 = *(const short8*)(Vt + (size_t)srow1 * S_LEN + scol);
            }
            if (kt <= ktp) {
                const short* Ksb = &KV[cur][0][0];
                const short* Vsb = &KV[cur][1][0];
                f32x16 st0, st1;
#pragma unroll
                for (int i = 0; i < 16; ++i) { st0[i] = 0.f; st1[i] = 0.f; }
                {
                    short8 kA, kB;
                    kA = *(const short8*)(Ksb + r0 * 64 + ((0 + ch) ^ sw));
                    kB = *(const short8*)(Ksb + r1 * 64 + ((0 + ch) ^ sw));
                    __builtin_amdgcn_s_setprio(1);
                    st0 = __builtin_amdgcn_mfma_f32_32x32x16_bf16(kA, qf0, st0, 0, 0, 0);
                    st1 = __builtin_amdgcn_mfma_f32_32x32x16_bf16(kB, qf0, st1, 0, 0, 0);
                    __builtin_amdgcn_s_setprio(0);
                    kA = *(const short8*)(Ksb + r0 * 64 + ((16 + ch) ^ sw));
                    kB = *(const short8*)(Ksb + r1 * 64 + ((16 + ch) ^ sw));
                    __builtin_amdgcn_s_setprio(1);
                    st0 = __builtin_amdgcn_mfma_f32_32x32x16_bf16(kA, qf1, st0, 0, 0, 0);
                    st1 = __builtin_amdgcn_mfma_f32_32x32x16_bf16(kB, qf1, st1, 0, 0, 0);
                    __builtin_amdgcn_s_setprio(0);
                    kA = *(const short8*)(Ksb + r0 * 64 + ((32 + ch) ^ sw));
                    kB = *(const short8*)(Ksb + r1 * 64 + ((32 + ch) ^ sw));
                    __builtin_amdgcn_s_setprio(1);
                    st0 = __builtin_amdgcn_mfma_f32_32x32x16_bf16(kA, qf2, st0, 0, 0, 0);
                    st1 = __builtin_amdgcn_mfma_f32_32x32x16_bf16(kB, qf2, st1, 0, 0, 0);
                    __builtin_amdgcn_s_setprio(0);
                    kA = *(const short8*)(Ksb + r0 * 64 + ((48 + ch) ^ sw));
                    kB = *(const short8*)(Ksb + r1 * 64 + ((48 + ch) ^ sw));
                    __builtin_amdgcn_s_setprio(1);
                    st0 = __builtin_amdgcn_mfma_f32_32x32x16_bf16(kA, qf3, st0, 0, 0, 0);
                    st1 = __builtin_amdgcn_mfma_f32_32x32x16_bf16(kB, qf3, st1, 0, 0, 0);
                    __builtin_amdgcn_s_setprio(0);
                }
                float p[32];
#pragma unroll
                for (int i = 0; i < 16; ++i) { p[i] = st0[i]; p[16 + i] = st1[i]; }
                if (kt == ktp) {
#pragma unroll
                    for (int i = 0; i < 32; ++i) {
                        int kl = (i & 3) + 8 * ((i >> 2) & 3) + 32 * (i >> 4) + 4 * hi;
                        if (kt * 64 + kl > q_g) p[i] = -1e30f;
                    }
                }
#pragma unroll
                for (int i = 0; i < 32; ++i) p[i] = exp2f(p[i]);
                float t[16];
#pragma unroll
                for (int i = 0; i < 16; ++i) t[i] = p[i] + p[i + 16];
#pragma unroll
                for (int i = 0; i < 8; ++i) t[i] = t[i] + t[i + 8];
#pragma unroll
                for (int i = 0; i < 4; ++i) t[i] = t[i] + t[i + 4];
                float rs = (t[0] + t[1]) + (t[2] + t[3]);
                rs += __shfl_xor(rs, 32);
                lrun += rs;
                {
                    unsigned u0 = cvtpk(p[0], p[1]);
                    unsigned u1 = cvtpk(p[2], p[3]);
                    unsigned u2 = cvtpk(p[4], p[5]);
                    unsigned u3 = cvtpk(p[6], p[7]);
                    plswap(u0, u2);
                    plswap(u1, u3);
                    short8 pfA = mk8(u0, u1, u2, u3);
                    unsigned u4 = cvtpk(p[8], p[9]);
                    unsigned u5 = cvtpk(p[10], p[11]);
                    unsigned u6 = cvtpk(p[12], p[13]);
                    unsigned u7 = cvtpk(p[14], p[15]);
                    plswap(u4, u6);
                    plswap(u5, u7);
                    short8 pfB = mk8(u4, u5, u6, u7);
                    short8 vA0 = *(const short8*)(Vsb + r0 * 64 + ((0 + ch) ^ sw));
                    short8 vB0 = *(const short8*)(Vsb + r1 * 64 + ((0 + ch) ^ sw));
                    short8 vA1 = *(const short8*)(Vsb + r0 * 64 + ((16 + ch) ^ sw));
                    short8 vB1 = *(const short8*)(Vsb + r1 * 64 + ((16 + ch) ^ sw));
                    __builtin_amdgcn_s_setprio(1);
                    accA = __builtin_amdgcn_mfma_f32_32x32x16_bf16(vA0, pfA, accA, 0, 0, 0);
                    accB = __builtin_amdgcn_mfma_f32_32x32x16_bf16(vB0, pfA, accB, 0, 0, 0);
                    accA = __builtin_amdgcn_mfma_f32_32x32x16_bf16(vA1, pfB, accA, 0, 0, 0);
                    accB = __builtin_amdgcn_mfma_f32_32x32x16_bf16(vB1, pfB, accB, 0, 0, 0);
                    __builtin_amdgcn_s_setprio(0);
                }
                {
                    unsigned u0 = cvtpk(p[16], p[17]);
                    unsigned u1 = cvtpk(p[18], p[19]);
                    unsigned u2 = cvtpk(p[20], p[21]);
                    unsigned u3 = cvtpk(p[22], p[23]);
                    plswap(u0, u2);
                    plswap(u1, u3);
                    short8 pfC = mk8(u0, u1, u2, u3);
                    unsigned u4 = cvtpk(p[24], p[25]);
                    unsigned u5 = cvtpk(p[26], p[27]);
                    unsigned u6 = cvtpk(p[28], p[29]);
                    unsigned u7 = cvtpk(p[30], p[31]);
                    plswap(u4, u6);
                    plswap(u5, u7);
                    short8 pfD = mk8(u4, u5, u6, u7);
                    short8 vA2 = *(const short8*)(Vsb + r0 * 64 + ((32 + ch) ^ sw));
                    short8 vB2 = *(const short8*)(Vsb + r1 * 64 + ((32 + ch) ^ sw));
                    short8 vA3 = *(const short8*)(Vsb + r0 * 64 + ((48 + ch) ^ sw));
                    short8 vB3 = *(const short8*)(Vsb + r1 * 64 + ((48 + ch) ^ sw));
                    __builtin_amdgcn_s_setprio(1);
                    accA = __builtin_amdgcn_mfma_f32_32x32x16_bf16(vA2, pfC, accA, 0, 0, 0);
                    accB = __builtin_amdgcn_mfma_f32_32x32x16_bf16(vB2, pfC, accB, 0, 0, 0);
                    accA = __builtin_amdgcn_mfma_f32_32x32x16_bf16(vA3, pfD, accA, 0, 0, 0);
                    accB = __builtin_amdgcn_mfma_f32_32x32x16_bf16(vB3, pfD, accB, 0, 0, 0);
                    __builtin_amdgcn_s_setprio(0);
                }
            }
            if (pf) {
                int nb = (kt + 1) & 1;
                *(short8*)(&KV[nb][0][wo0]) = pk0;
                *(short8*)(&KV[nb][0][wo1]) = pk1;
                *(short8*)(&KV[nb][1][wo0]) = pv0;
                *(short8*)(&KV[nb][1][wo1]) = pv1;
            }
        }

        float inv = 1.0f / lrun;
        short* cb = ctx + ((size_t)(b * S_LEN + q_g)) * HIDN + h * DHEAD;
#pragma unroll
        for (int i = 0; i < 16; ++i) {
            int d0 = (i & 3) + 8 * (i >> 2) + 4 * hi;
            cb[d0] = f2bf(accA[i] * inv);
            cb[32 + d0] = f2bf(accB[i] * inv);
        }
    }
}

extern "C" void kernel_launch(void* const* d_in, const int* in_sizes, int n_in,
                              void* d_out, int out_size, void* d_ws, size_t ws_size,
                              hipStream_t stream) {
    const float* q  = (const float*)d_in[0];
    const float* k  = (const float*)d_in[1];
    const float* v  = (const float*)d_in[2];
    // d_in[3] = attn_mask: structurally causal, not read.
    const float* Wq = (const float*)d_in[4];
    const float* bq = (const float*)d_in[5];
    const float* Wk = (const float*)d_in[6];
    const float* bk = (const float*)d_in[7];
    const float* Wv = (const float*)d_in[8];
    const float* bv = (const float*)d_in[9];
    const float* Wo = (const float*)d_in[10];
    const float* bo = (const float*)d_in[11];

    char* ws = (char*)d_ws;
    const size_t ACT = (size_t)8192 * 1024 * 2;
    const size_t WSZ = (size_t)1024 * 1024 * 2;
    short* Qh  = (short*)(ws);
    short* Kh  = (short*)(ws + ACT);
    short* VhT = (short*)(ws + 2 * ACT);
    short* qb  = (short*)(ws + 3 * ACT);
    short* kb  = (short*)(ws + 4 * ACT);
    short* vb  = (short*)(ws + 5 * ACT);
    short* ctx = qb;
    short* Wqb = (short*)(ws + 6 * ACT);
    short* Wkb = (short*)(ws + 6 * ACT + WSZ);
    short* Wvb = (short*)(ws + 6 * ACT + 2 * WSZ);
    short* Wob = (short*)(ws + 6 * ACT + 3 * WSZ);

    cvt_all<<<14336, 256, 0, stream>>>(q, k, v, Wq, Wk, Wv, Wo,
                                       qb, kb, vb, Wqb, Wkb, Wvb, Wob);

    const float QSCALE = 0.125f * 1.44269504088896340736f;
    gemm_qkv<<<1536, 256, 0, stream>>>(qb, kb, vb, Wqb, Wkb, Wvb, bq, bk, bv,
                                       Qh, Kh, VhT, QSCALE);

    attn_kernel<<<512, 256, 0, stream>>>(Qh, Kh, VhT, ctx);

    gemm_out<<<512, 256, 0, stream>>>(ctx, Wob, bo, (float*)d_out);
}

// Round 15
// 183.398 us; speedup vs baseline: 1.1955x; 1.0880x over previous
//
#include <hip/hip_runtime.h>

typedef __attribute__((ext_vector_type(8))) short short8;
typedef __attribute__((ext_vector_type(4))) float f32x4;
typedef __attribute__((ext_vector_type(16))) float f32x16;

#define S_LEN 2048
#define HIDN  1024
#define NHEAD 16
#define DHEAD 64

__device__ __forceinline__ short f2bf(float x) {
    unsigned u = __float_as_uint(x);
    u += 0x7fffu + ((u >> 16) & 1u);
    return (short)(u >> 16);
}

typedef const __attribute__((address_space(1))) void* gas_ptr;
typedef __attribute__((address_space(3))) void* las_ptr;

__device__ __forceinline__ void gload_lds16(const void* g, void* l) {
    __builtin_amdgcn_global_load_lds((gas_ptr)g, (las_ptr)l, 16, 0, 0);
}

__device__ __forceinline__ unsigned cvtpk(float lo, float hi_) {
    unsigned r;
    asm("v_cvt_pk_bf16_f32 %0, %1, %2" : "=v"(r) : "v"(lo), "v"(hi_));
    return r;
}

__device__ __forceinline__ void plswap(unsigned& x, unsigned& y) {
    asm("v_permlane32_swap_b32 %0, %1" : "+&v"(x), "+&v"(y));
}

__device__ __forceinline__ short8 mk8(unsigned a, unsigned b, unsigned c, unsigned d) {
    union { unsigned u[4]; short8 s; } t;
    t.u[0] = a; t.u[1] = b; t.u[2] = c; t.u[3] = d;
    return t.s;
}

// ---------------- fp32 -> bf16. Weights FIRST, activations LAST (L3-warm for gemm_qkv) ----------------
__global__ __launch_bounds__(256) void cvt_all(const float* __restrict__ q,
                                               const float* __restrict__ k,
                                               const float* __restrict__ v,
                                               const float* __restrict__ Wq,
                                               const float* __restrict__ Wk,
                                               const float* __restrict__ Wv,
                                               const float* __restrict__ Wo,
                                               short* __restrict__ qb,
                                               short* __restrict__ kb,
                                               short* __restrict__ vb,
                                               short* __restrict__ wqb,
                                               short* __restrict__ wkb,
                                               short* __restrict__ wvb,
                                               short* __restrict__ wob) {
    int bid = blockIdx.x;
    const float* in;
    short* out;
    int base;
    if (bid < 2048) {
        int wsel = bid >> 9;
        base = bid & 511;
        in  = wsel == 0 ? Wq  : wsel == 1 ? Wk  : wsel == 2 ? Wv  : Wo;
        out = wsel == 0 ? wqb : wsel == 1 ? wkb : wsel == 2 ? wvb : wob;
    } else if (bid < 6144)  { in = q; out = qb; base = bid - 2048; }
    else if (bid < 10240)   { in = k; out = kb; base = bid - 6144; }
    else                    { in = v; out = vb; base = bid - 10240; }
    int i = (base * 256 + threadIdx.x) * 8;
    float4 a = *(const float4*)(in + i);
    float4 b = *(const float4*)(in + i + 4);
    short8 o;
    o[0] = f2bf(a.x); o[1] = f2bf(a.y); o[2] = f2bf(a.z); o[3] = f2bf(a.w);
    o[4] = f2bf(b.x); o[5] = f2bf(b.y); o[6] = f2bf(b.z); o[7] = f2bf(b.w);
    *(short8*)(out + i) = o;
}

// ---------------- GEMM core: bf16 x bf16, BK=64, double-buffered, XOR-swizzled ----------------
__device__ __forceinline__ void gemm_k64_db(const short* A, const short* Wb,
                                            short* As0, short* As1,
                                            short* Bs0, short* Bs1,
                                            f32x4 acc[4][4], int m0, int n0) {
    int tid = threadIdx.x;
    int w = tid >> 6, l = tid & 63, g = l >> 4, r = l & 15;
    int wm = w >> 1, wn = w & 1;
    int r7 = r & 7;

    int rowin = l >> 3;
    int scol = ((l & 7) ^ rowin) * 8;   // pre-swizzled source col (shorts)
    int dst = l * 8;

#pragma unroll
    for (int i = 0; i < 4; i++) {
        int c = w * 4 + i;
        int row = c * 8 + rowin;
        gload_lds16(A + (size_t)(m0 + row) * HIDN + scol, As0 + c * 512 + dst);
        gload_lds16(Wb + (size_t)(n0 + row) * HIDN + scol, Bs0 + c * 512 + dst);
    }
    __syncthreads();

    for (int kt = 0; kt < HIDN / 64; ++kt) {
        short* Asc = (kt & 1) ? As1 : As0;
        short* Bsc = (kt & 1) ? Bs1 : Bs0;
        short* Asn = (kt & 1) ? As0 : As1;
        short* Bsn = (kt & 1) ? Bs0 : Bs1;
        if (kt + 1 < HIDN / 64) {
            int kc = (kt + 1) * 64;
#pragma unroll
            for (int i = 0; i < 4; i++) {
                int c = w * 4 + i;
                int row = c * 8 + rowin;
                gload_lds16(A + (size_t)(m0 + row) * HIDN + kc + scol, Asn + c * 512 + dst);
                gload_lds16(Wb + (size_t)(n0 + row) * HIDN + kc + scol, Bsn + c * 512 + dst);
            }
        }
        short8 af[4][2], bfr[4][2];
#pragma unroll
        for (int i = 0; i < 4; i++)
#pragma unroll
            for (int ks = 0; ks < 2; ks++)
                af[i][ks] = *(const short8*)(Asc + (wm * 64 + i * 16 + r) * 64 +
                                             ((((ks << 2) + g) ^ r7) << 3));
#pragma unroll
        for (int j = 0; j < 4; j++)
#pragma unroll
            for (int ks = 0; ks < 2; ks++)
                bfr[j][ks] = *(const short8*)(Bsc + (wn * 64 + j * 16 + r) * 64 +
                                              ((((ks << 2) + g) ^ r7) << 3));
        __builtin_amdgcn_s_setprio(1);
#pragma unroll
        for (int i = 0; i < 4; i++)
#pragma unroll
            for (int j = 0; j < 4; j++) {
                acc[i][j] = __builtin_amdgcn_mfma_f32_16x16x32_bf16(af[i][0], bfr[j][0], acc[i][j], 0, 0, 0);
                acc[i][j] = __builtin_amdgcn_mfma_f32_16x16x32_bf16(af[i][1], bfr[j][1], acc[i][j], 0, 0, 0);
            }
        __builtin_amdgcn_s_setprio(0);
        __syncthreads();
    }
}

__global__ __launch_bounds__(256) void gemm_qkv(const short* __restrict__ qb,
                                                const short* __restrict__ kb,
                                                const short* __restrict__ vb,
                                                const short* __restrict__ Wqb,
                                                const short* __restrict__ Wkb,
                                                const short* __restrict__ Wvb,
                                                const float* __restrict__ bq,
                                                const float* __restrict__ bk,
                                                const float* __restrict__ bv,
                                                short* __restrict__ Qh,
                                                short* __restrict__ Kh,
                                                short* __restrict__ VhT,
                                                float qscale) {
    int which = blockIdx.x >> 9;
    int bid = blockIdx.x & 511;
    const short* A = which == 0 ? qb : which == 1 ? kb : vb;
    const short* Wb = which == 0 ? Wqb : which == 1 ? Wkb : Wvb;
    const float* bias = which == 0 ? bq : which == 1 ? bk : bv;
    short* Out = which == 0 ? Qh : which == 1 ? Kh : VhT;
    float oscale = which == 0 ? qscale : 1.0f;
    int omode = which == 2 ? 1 : 0;

    int mt = bid & 63, nt = bid >> 6;
    int m0 = mt * 128, n0 = nt * 128;
    int tid = threadIdx.x;
    int w = tid >> 6, l = tid & 63, g = l >> 4, r = l & 15;
    int wm = w >> 1, wn = w & 1;

    __shared__ short As0[128 * 64], As1[128 * 64];
    __shared__ short Bs0[128 * 64], Bs1[128 * 64];

    f32x4 acc[4][4];
#pragma unroll
    for (int i = 0; i < 4; i++)
#pragma unroll
        for (int j = 0; j < 4; j++) acc[i][j] = (f32x4){0.f, 0.f, 0.f, 0.f};

    gemm_k64_db(A, Wb, As0, As1, Bs0, Bs1, acc, m0, n0);

#pragma unroll
    for (int j = 0; j < 4; j++) {
        int n_g = n0 + wn * 64 + j * 16 + r;
        float bv2 = bias[n_g];
        int h = n_g >> 6, d = n_g & 63;
#pragma unroll
        for (int i = 0; i < 4; i++) {
#pragma unroll
            for (int rr = 0; rr < 4; rr++) {
                int m_g = m0 + wm * 64 + i * 16 + g * 4 + rr;
                float val = (acc[i][j][rr] + bv2) * oscale;
                int b = m_g >> 11, s = m_g & 2047;
                size_t idx = (omode == 0)
                    ? (((size_t)(b * NHEAD + h)) * S_LEN + s) * DHEAD + d
                    : (((size_t)(b * NHEAD + h)) * DHEAD + d) * S_LEN + s;
                Out[idx] = f2bf(val);
            }
        }
    }
}

__global__ __launch_bounds__(256) void gemm_out(const short* __restrict__ A,
                                                const short* __restrict__ Wb,
                                                const float* __restrict__ bias,
                                                float* __restrict__ Out) {
    int mt = blockIdx.x & 63, nt = blockIdx.x >> 6;
    int m0 = mt * 128, n0 = nt * 128;
    int tid = threadIdx.x;
    int w = tid >> 6, l = tid & 63, g = l >> 4, r = l & 15;
    int wm = w >> 1, wn = w & 1;

    __shared__ short As0[128 * 64], As1[128 * 64];
    __shared__ short Bs0[128 * 64], Bs1[128 * 64];

    f32x4 acc[4][4];
#pragma unroll
    for (int i = 0; i < 4; i++)
#pragma unroll
        for (int j = 0; j < 4; j++) acc[i][j] = (f32x4){0.f, 0.f, 0.f, 0.f};

    gemm_k64_db(A, Wb, As0, As1, Bs0, Bs1, acc, m0, n0);

#pragma unroll
    for (int j = 0; j < 4; j++) {
        int n_g = n0 + wn * 64 + j * 16 + r;
        float bv = bias[n_g];
#pragma unroll
        for (int i = 0; i < 4; i++) {
#pragma unroll
            for (int rr = 0; rr < 4; rr++) {
                int m_g = m0 + wm * 64 + i * 16 + g * 4 + rr;
                Out[(size_t)m_g * HIDN + n_g] = acc[i][j][rr] + bv;
            }
        }
    }
}

// ---------------- flash attention: 512-thread blocks, concurrent paired q-tiles ----------------
// grid = 512 x 512 threads (8 waves). Waves 0-3 compute qtA = j, waves 4-7 qtB = 15-j,
// SHARING one K/V stream (j's k-prefix subsets 15-j's): nt = 32-2j stage iters (vs 36
// sequential). Decode: m=bid>>8, u=bid&255, q2=u>>6, j = m ? 7-q2 : q2 -> co-resident
// blocks (bid, bid+256) have lengths summing to 50 iters, uniform across CUs.
// bh = ((u>>3)&7)*8 + (u&7) -> bid%8 = bh%8: all 8 blocks of a bh on one XCD (K/V L2-res).
// Occupancy: 2 blocks/CU x 8 waves = 16 waves/CU (50% cap, 2x the paired-sequential form).
// Un-normalized exp2 softmax (no running max): |logits| <~ 10 binades, fp32 safe.
__global__ __launch_bounds__(512) void attn_kernel(const short* __restrict__ Qh,
                                                   const short* __restrict__ Kh,
                                                   const short* __restrict__ VhT,
                                                   short* __restrict__ ctx) {
    int bid = blockIdx.x;
    int m = bid >> 8;
    int u = bid & 255;
    int q2 = u >> 6;
    int bh = ((u >> 3) & 7) * 8 + (u & 7);
    int j = m ? (7 - q2) : q2;
    int qtB = 15 - j;
    int tid = threadIdx.x;
    int w = tid >> 6, l = tid & 63;
    int ql = l & 31, hi = l >> 5;
    int wq = w & 3, grp = w >> 2;
    int qt = grp ? qtB : j;

    __shared__ short KV[2][2][64 * 64];  // 32 KB

    const short* Qb = Qh + (size_t)bh * (S_LEN * DHEAD);
    const short* Kb = Kh + (size_t)bh * (S_LEN * DHEAD);
    const short* Vb = VhT + (size_t)bh * (DHEAD * S_LEN);

    int srow = tid >> 3;                 // 0..63: 512 threads cover the full 64-row tile
    int scol = (tid & 7) * 8;            // shorts
    int wo = srow * 64 + (scol ^ ((srow & 7) << 3));

    int r0 = ql, r1 = 32 + ql;
    int sw = (ql & 7) << 3;
    int ch = hi * 8;
    int b = bh >> 4, h = bh & 15;

    int q_g = qt * 128 + wq * 32 + ql;
    const short* qp = Qb + (size_t)q_g * DHEAD + hi * 8;
    short8 qf0 = *(const short8*)(qp);
    short8 qf1 = *(const short8*)(qp + 16);
    short8 qf2 = *(const short8*)(qp + 32);
    short8 qf3 = *(const short8*)(qp + 48);

    f32x16 accA, accB;
#pragma unroll
    for (int i = 0; i < 16; ++i) { accA[i] = 0.f; accB[i] = 0.f; }
    float lrun = 0.f;

    int ktp = (qt * 128 + wq * 32) >> 6;   // this wave's diagonal tile
    int nt = 2 * qtB + 2;                  // shared stream length (= longest group)

    {  // prologue: stage tile 0 into buf 0 (one 16B K + one 16B V per thread)
        short8 k0 = *(const short8*)(Kb + srow * 64 + scol);
        short8 v0 = *(const short8*)(Vb + (size_t)srow * S_LEN + scol);
        *(short8*)(&KV[0][0][wo]) = k0;
        *(short8*)(&KV[0][1][wo]) = v0;
    }

    for (int kt = 0; kt < nt; ++kt) {
        __syncthreads();
        int cur = kt & 1;
        short8 pk0, pv0;
        bool pf = (kt + 1 < nt);
        if (pf) {
            pk0 = *(const short8*)(Kb + (kt + 1) * (64 * DHEAD) + srow * 64 + scol);
            pv0 = *(const short8*)(Vb + (size_t)srow * S_LEN + (kt + 1) * 64 + scol);
        }
        if (kt <= ktp) {
            const short* Ksb = &KV[cur][0][0];
            const short* Vsb = &KV[cur][1][0];
            f32x16 st0, st1;
#pragma unroll
            for (int i = 0; i < 16; ++i) { st0[i] = 0.f; st1[i] = 0.f; }
            {
                short8 kA, kB;
                kA = *(const short8*)(Ksb + r0 * 64 + ((0 + ch) ^ sw));
                kB = *(const short8*)(Ksb + r1 * 64 + ((0 + ch) ^ sw));
                __builtin_amdgcn_s_setprio(1);
                st0 = __builtin_amdgcn_mfma_f32_32x32x16_bf16(kA, qf0, st0, 0, 0, 0);
                st1 = __builtin_amdgcn_mfma_f32_32x32x16_bf16(kB, qf0, st1, 0, 0, 0);
                __builtin_amdgcn_s_setprio(0);
                kA = *(const short8*)(Ksb + r0 * 64 + ((16 + ch) ^ sw));
                kB = *(const short8*)(Ksb + r1 * 64 + ((16 + ch) ^ sw));
                __builtin_amdgcn_s_setprio(1);
                st0 = __builtin_amdgcn_mfma_f32_32x32x16_bf16(kA, qf1, st0, 0, 0, 0);
                st1 = __builtin_amdgcn_mfma_f32_32x32x16_bf16(kB, qf1, st1, 0, 0, 0);
                __builtin_amdgcn_s_setprio(0);
                kA = *(const short8*)(Ksb + r0 * 64 + ((32 + ch) ^ sw));
                kB = *(const short8*)(Ksb + r1 * 64 + ((32 + ch) ^ sw));
                __builtin_amdgcn_s_setprio(1);
                st0 = __builtin_amdgcn_mfma_f32_32x32x16_bf16(kA, qf2, st0, 0, 0, 0);
                st1 = __builtin_amdgcn_mfma_f32_32x32x16_bf16(kB, qf2, st1, 0, 0, 0);
                __builtin_amdgcn_s_setprio(0);
                kA = *(const short8*)(Ksb + r0 * 64 + ((48 + ch) ^ sw));
                kB = *(const short8*)(Ksb + r1 * 64 + ((48 + ch) ^ sw));
                __builtin_amdgcn_s_setprio(1);
                st0 = __builtin_amdgcn_mfma_f32_32x32x16_bf16(kA, qf3, st0, 0, 0, 0);
                st1 = __builtin_amdgcn_mfma_f32_32x32x16_bf16(kB, qf3, st1, 0, 0, 0);
                __builtin_amdgcn_s_setprio(0);
            }
            float p[32];
#pragma unroll
            for (int i = 0; i < 16; ++i) { p[i] = st0[i]; p[16 + i] = st1[i]; }
            if (kt == ktp) {  // diagonal tile: per-element causal mask
#pragma unroll
                for (int i = 0; i < 32; ++i) {
                    int kl = (i & 3) + 8 * ((i >> 2) & 3) + 32 * (i >> 4) + 4 * hi;
                    if (kt * 64 + kl > q_g) p[i] = -1e30f;
                }
            }
#pragma unroll
            for (int i = 0; i < 32; ++i) p[i] = exp2f(p[i]);
            float t[16];
#pragma unroll
            for (int i = 0; i < 16; ++i) t[i] = p[i] + p[i + 16];
#pragma unroll
            for (int i = 0; i < 8; ++i) t[i] = t[i] + t[i + 8];
#pragma unroll
            for (int i = 0; i < 4; ++i) t[i] = t[i] + t[i + 4];
            float rs = (t[0] + t[1]) + (t[2] + t[3]);
            rs += __shfl_xor(rs, 32);
            lrun += rs;
            {
                unsigned u0 = cvtpk(p[0], p[1]);
                unsigned u1 = cvtpk(p[2], p[3]);
                unsigned u2 = cvtpk(p[4], p[5]);
                unsigned u3 = cvtpk(p[6], p[7]);
                plswap(u0, u2);
                plswap(u1, u3);
                short8 pfA = mk8(u0, u1, u2, u3);
                unsigned u4 = cvtpk(p[8], p[9]);
                unsigned u5 = cvtpk(p[10], p[11]);
                unsigned u6 = cvtpk(p[12], p[13]);
                unsigned u7 = cvtpk(p[14], p[15]);
                plswap(u4, u6);
                plswap(u5, u7);
                short8 pfB = mk8(u4, u5, u6, u7);
                short8 vA0 = *(const short8*)(Vsb + r0 * 64 + ((0 + ch) ^ sw));
                short8 vB0 = *(const short8*)(Vsb + r1 * 64 + ((0 + ch) ^ sw));
                short8 vA1 = *(const short8*)(Vsb + r0 * 64 + ((16 + ch) ^ sw));
                short8 vB1 = *(const short8*)(Vsb + r1 * 64 + ((16 + ch) ^ sw));
                __builtin_amdgcn_s_setprio(1);
                accA = __builtin_amdgcn_mfma_f32_32x32x16_bf16(vA0, pfA, accA, 0, 0, 0);
                accB = __builtin_amdgcn_mfma_f32_32x32x16_bf16(vB0, pfA, accB, 0, 0, 0);
                accA = __builtin_amdgcn_mfma_f32_32x32x16_bf16(vA1, pfB, accA, 0, 0, 0);
                accB = __builtin_amdgcn_mfma_f32_32x32x16_bf16(vB1, pfB, accB, 0, 0, 0);
                __builtin_amdgcn_s_setprio(0);
            }
            {
                unsigned u0 = cvtpk(p[16], p[17]);
                unsigned u1 = cvtpk(p[18], p[19]);
                unsigned u2 = cvtpk(p[20], p[21]);
                unsigned u3 = cvtpk(p[22], p[23]);
                plswap(u0, u2);
                plswap(u1, u3);
                short8 pfC = mk8(u0, u1, u2, u3);
                unsigned u4 = cvtpk(p[24], p[25]);
                unsigned u5 = cvtpk(p[26], p[27]);
                unsigned u6 = cvtpk(p[28], p[29]);
                unsigned u7 = cvtpk(p[30], p[31]);
                plswap(u4, u6);
                plswap(u5, u7);
                short8 pfD = mk8(u4, u5, u6, u7);
                short8 vA2 = *(const short8*)(Vsb + r0 * 64 + ((32 + ch) ^ sw));
                short8 vB2 = *(const short8*)(Vsb + r1 * 64 + ((32 + ch) ^ sw));
                short8 vA3 = *(const short8*)(Vsb + r0 * 64 + ((48 + ch) ^ sw));
                short8 vB3 = *(const short8*)(Vsb + r1 * 64 + ((48 + ch) ^ sw));
                __builtin_amdgcn_s_setprio(1);
                accA = __builtin_amdgcn_mfma_f32_32x32x16_bf16(vA2, pfC, accA, 0, 0, 0);
                accB = __builtin_amdgcn_mfma_f32_32x32x16_bf16(vB2, pfC, accB, 0, 0, 0);
                accA = __builtin_amdgcn_mfma_f32_32x32x16_bf16(vA3, pfD, accA, 0, 0, 0);
                accB = __builtin_amdgcn_mfma_f32_32x32x16_bf16(vB3, pfD, accB, 0, 0, 0);
                __builtin_amdgcn_s_setprio(0);
            }
        }
        if (pf) {
            int nb = (kt + 1) & 1;
            *(short8*)(&KV[nb][0][wo]) = pk0;
            *(short8*)(&KV[nb][1][wo]) = pv0;
        }
    }

    float inv = 1.0f / lrun;
    short* cb = ctx + ((size_t)(b * S_LEN + q_g)) * HIDN + h * DHEAD;
#pragma unroll
    for (int i = 0; i < 16; ++i) {
        int d0 = (i & 3) + 8 * (i >> 2) + 4 * hi;
        cb[d0] = f2bf(accA[i] * inv);
        cb[32 + d0] = f2bf(accB[i] * inv);
    }
}

extern "C" void kernel_launch(void* const* d_in, const int* in_sizes, int n_in,
                              void* d_out, int out_size, void* d_ws, size_t ws_size,
                              hipStream_t stream) {
    const float* q  = (const float*)d_in[0];
    const float* k  = (const float*)d_in[1];
    const float* v  = (const float*)d_in[2];
    // d_in[3] = attn_mask: structurally causal, not read.
    const float* Wq = (const float*)d_in[4];
    const float* bq = (const float*)d_in[5];
    const float* Wk = (const float*)d_in[6];
    const float* bk = (const float*)d_in[7];
    const float* Wv = (const float*)d_in[8];
    const float* bv = (const float*)d_in[9];
    const float* Wo = (const float*)d_in[10];
    const float* bo = (const float*)d_in[11];

    char* ws = (char*)d_ws;
    const size_t ACT = (size_t)8192 * 1024 * 2;
    const size_t WSZ = (size_t)1024 * 1024 * 2;
    short* Qh  = (short*)(ws);
    short* Kh  = (short*)(ws + ACT);
    short* VhT = (short*)(ws + 2 * ACT);
    short* qb  = (short*)(ws + 3 * ACT);
    short* kb  = (short*)(ws + 4 * ACT);
    short* vb  = (short*)(ws + 5 * ACT);
    short* ctx = qb;
    short* Wqb = (short*)(ws + 6 * ACT);
    short* Wkb = (short*)(ws + 6 * ACT + WSZ);
    short* Wvb = (short*)(ws + 6 * ACT + 2 * WSZ);
    short* Wob = (short*)(ws + 6 * ACT + 3 * WSZ);

    cvt_all<<<14336, 256, 0, stream>>>(q, k, v, Wq, Wk, Wv, Wo,
                                       qb, kb, vb, Wqb, Wkb, Wvb, Wob);

    const float QSCALE = 0.125f * 1.44269504088896340736f;
    gemm_qkv<<<1536, 256, 0, stream>>>(qb, kb, vb, Wqb, Wkb, Wvb, bq, bk, bv,
                                       Qh, Kh, VhT, QSCALE);

    attn_kernel<<<512, 512, 0, stream>>>(Qh, Kh, VhT, ctx);

    gemm_out<<<512, 256, 0, stream>>>(ctx, Wob, bo, (float*)d_out);
}

// Round 16
// 178.843 us; speedup vs baseline: 1.2259x; 1.0255x over previous
//
#include <hip/hip_runtime.h>

typedef __attribute__((ext_vector_type(8))) short short8;
typedef __attribute__((ext_vector_type(4))) float f32x4;
typedef __attribute__((ext_vector_type(16))) float f32x16;

#define S_LEN 2048
#define HIDN  1024
#define NHEAD 16
#define DHEAD 64

__device__ __forceinline__ short f2bf(float x) {
    unsigned u = __float_as_uint(x);
    u += 0x7fffu + ((u >> 16) & 1u);
    return (short)(u >> 16);
}

typedef const __attribute__((address_space(1))) void* gas_ptr;
typedef __attribute__((address_space(3))) void* las_ptr;

__device__ __forceinline__ void gload_lds16(const void* g, void* l) {
    __builtin_amdgcn_global_load_lds((gas_ptr)g, (las_ptr)l, 16, 0, 0);
}

__device__ __forceinline__ unsigned cvtpk(float lo, float hi_) {
    unsigned r;
    asm("v_cvt_pk_bf16_f32 %0, %1, %2" : "=v"(r) : "v"(lo), "v"(hi_));
    return r;
}

__device__ __forceinline__ void plswap(unsigned& x, unsigned& y) {
    asm("v_permlane32_swap_b32 %0, %1" : "+&v"(x), "+&v"(y));
}

__device__ __forceinline__ short8 mk8(unsigned a, unsigned b, unsigned c, unsigned d) {
    union { unsigned u[4]; short8 s; } t;
    t.u[0] = a; t.u[1] = b; t.u[2] = c; t.u[3] = d;
    return t.s;
}

// ---------------- fp32 -> bf16. Weights FIRST, activations LAST (L3-warm for gemm_qkv) ----------------
__global__ __launch_bounds__(256) void cvt_all(const float* __restrict__ q,
                                               const float* __restrict__ k,
                                               const float* __restrict__ v,
                                               const float* __restrict__ Wq,
                                               const float* __restrict__ Wk,
                                               const float* __restrict__ Wv,
                                               const float* __restrict__ Wo,
                                               short* __restrict__ qb,
                                               short* __restrict__ kb,
                                               short* __restrict__ vb,
                                               short* __restrict__ wqb,
                                               short* __restrict__ wkb,
                                               short* __restrict__ wvb,
                                               short* __restrict__ wob) {
    int bid = blockIdx.x;
    const float* in;
    short* out;
    int base;
    if (bid < 2048) {
        int wsel = bid >> 9;
        base = bid & 511;
        in  = wsel == 0 ? Wq  : wsel == 1 ? Wk  : wsel == 2 ? Wv  : Wo;
        out = wsel == 0 ? wqb : wsel == 1 ? wkb : wsel == 2 ? wvb : wob;
    } else if (bid < 6144)  { in = q; out = qb; base = bid - 2048; }
    else if (bid < 10240)   { in = k; out = kb; base = bid - 6144; }
    else                    { in = v; out = vb; base = bid - 10240; }
    int i = (base * 256 + threadIdx.x) * 8;
    float4 a = *(const float4*)(in + i);
    float4 b = *(const float4*)(in + i + 4);
    short8 o;
    o[0] = f2bf(a.x); o[1] = f2bf(a.y); o[2] = f2bf(a.z); o[3] = f2bf(a.w);
    o[4] = f2bf(b.x); o[5] = f2bf(b.y); o[6] = f2bf(b.z); o[7] = f2bf(b.w);
    *(short8*)(out + i) = o;
}

// ---------------- GEMM core: 512 threads (8 waves, 2x4 grid), BK=64 dbuf, XOR-swizzled ----------------
// Same 128x128 tile / 64KB LDS as R15, but 8 waves -> 2 blocks/CU = 16 waves/CU (50% cap,
// 2x the 256-thread version). Each wave owns a 64x32 sub-tile: acc[4][2], 16 MFMA/kt.
// Staging: slot s = w*64 + i*512 + l covers all 1024 16B-chunks once; linear LDS dest,
// pre-swizzled source col (cs ^ (row&7)); frag reads XOR ^(r&7) (rows == r mod 8).
__device__ __forceinline__ void gemm_k64_db8(const short* A, const short* Wb,
                                             short* As0, short* As1,
                                             short* Bs0, short* Bs1,
                                             f32x4 acc[4][2], int m0, int n0) {
    int tid = threadIdx.x;
    int w = tid >> 6, l = tid & 63, g = l >> 4, r = l & 15;
    int wm = w >> 2, wn = w & 3;
    int r7 = r & 7;

    int s0 = w * 64 + l, s1 = s0 + 512;
    int row0 = s0 >> 3, src0 = (((s0 & 7) ^ (row0 & 7))) * 8;
    int row1 = s1 >> 3, src1 = (((s1 & 7) ^ (row1 & 7))) * 8;
    int d0 = s0 * 8, d1 = s1 * 8;

    // prologue: tile 0 -> buf 0
    gload_lds16(A + (size_t)(m0 + row0) * HIDN + src0, As0 + d0);
    gload_lds16(A + (size_t)(m0 + row1) * HIDN + src1, As0 + d1);
    gload_lds16(Wb + (size_t)(n0 + row0) * HIDN + src0, Bs0 + d0);
    gload_lds16(Wb + (size_t)(n0 + row1) * HIDN + src1, Bs0 + d1);
    __syncthreads();

    for (int kt = 0; kt < HIDN / 64; ++kt) {
        short* Asc = (kt & 1) ? As1 : As0;
        short* Bsc = (kt & 1) ? Bs1 : Bs0;
        short* Asn = (kt & 1) ? As0 : As1;
        short* Bsn = (kt & 1) ? Bs0 : Bs1;
        if (kt + 1 < HIDN / 64) {   // prefetch; flies during this MFMA block
            int kc = (kt + 1) * 64;
            gload_lds16(A + (size_t)(m0 + row0) * HIDN + kc + src0, Asn + d0);
            gload_lds16(A + (size_t)(m0 + row1) * HIDN + kc + src1, Asn + d1);
            gload_lds16(Wb + (size_t)(n0 + row0) * HIDN + kc + src0, Bsn + d0);
            gload_lds16(Wb + (size_t)(n0 + row1) * HIDN + kc + src1, Bsn + d1);
        }
        short8 af[4][2], bfr[2][2];
#pragma unroll
        for (int i = 0; i < 4; i++)
#pragma unroll
            for (int ks = 0; ks < 2; ks++)
                af[i][ks] = *(const short8*)(Asc + (wm * 64 + i * 16 + r) * 64 +
                                             ((((ks << 2) + g) ^ r7) << 3));
#pragma unroll
        for (int j = 0; j < 2; j++)
#pragma unroll
            for (int ks = 0; ks < 2; ks++)
                bfr[j][ks] = *(const short8*)(Bsc + (wn * 32 + j * 16 + r) * 64 +
                                              ((((ks << 2) + g) ^ r7) << 3));
        __builtin_amdgcn_s_setprio(1);
#pragma unroll
        for (int i = 0; i < 4; i++)
#pragma unroll
            for (int j = 0; j < 2; j++) {
                acc[i][j] = __builtin_amdgcn_mfma_f32_16x16x32_bf16(af[i][0], bfr[j][0], acc[i][j], 0, 0, 0);
                acc[i][j] = __builtin_amdgcn_mfma_f32_16x16x32_bf16(af[i][1], bfr[j][1], acc[i][j], 0, 0, 0);
            }
        __builtin_amdgcn_s_setprio(0);
        __syncthreads();
    }
}

__global__ __launch_bounds__(512) void gemm_qkv(const short* __restrict__ qb,
                                                const short* __restrict__ kb,
                                                const short* __restrict__ vb,
                                                const short* __restrict__ Wqb,
                                                const short* __restrict__ Wkb,
                                                const short* __restrict__ Wvb,
                                                const float* __restrict__ bq,
                                                const float* __restrict__ bk,
                                                const float* __restrict__ bv,
                                                short* __restrict__ Qh,
                                                short* __restrict__ Kh,
                                                short* __restrict__ VhT,
                                                float qscale) {
    int which = blockIdx.x >> 9;
    int bid = blockIdx.x & 511;
    const short* A = which == 0 ? qb : which == 1 ? kb : vb;
    const short* Wb = which == 0 ? Wqb : which == 1 ? Wkb : Wvb;
    const float* bias = which == 0 ? bq : which == 1 ? bk : bv;
    short* Out = which == 0 ? Qh : which == 1 ? Kh : VhT;
    float oscale = which == 0 ? qscale : 1.0f;
    int omode = which == 2 ? 1 : 0;

    int mt = bid & 63, nt = bid >> 6;
    int m0 = mt * 128, n0 = nt * 128;
    int tid = threadIdx.x;
    int w = tid >> 6, l = tid & 63, g = l >> 4, r = l & 15;
    int wm = w >> 2, wn = w & 3;

    __shared__ short As0[128 * 64], As1[128 * 64];
    __shared__ short Bs0[128 * 64], Bs1[128 * 64];   // 64 KB

    f32x4 acc[4][2];
#pragma unroll
    for (int i = 0; i < 4; i++)
#pragma unroll
        for (int j = 0; j < 2; j++) acc[i][j] = (f32x4){0.f, 0.f, 0.f, 0.f};

    gemm_k64_db8(A, Wb, As0, As1, Bs0, Bs1, acc, m0, n0);

#pragma unroll
    for (int j = 0; j < 2; j++) {
        int n_g = n0 + wn * 32 + j * 16 + r;
        float bv2 = bias[n_g];
        int h = n_g >> 6, d = n_g & 63;
#pragma unroll
        for (int i = 0; i < 4; i++) {
#pragma unroll
            for (int rr = 0; rr < 4; rr++) {
                int m_g = m0 + wm * 64 + i * 16 + g * 4 + rr;
                float val = (acc[i][j][rr] + bv2) * oscale;
                int b = m_g >> 11, s = m_g & 2047;
                size_t idx = (omode == 0)
                    ? (((size_t)(b * NHEAD + h)) * S_LEN + s) * DHEAD + d
                    : (((size_t)(b * NHEAD + h)) * DHEAD + d) * S_LEN + s;
                Out[idx] = f2bf(val);
            }
        }
    }
}

__global__ __launch_bounds__(512) void gemm_out(const short* __restrict__ A,
                                                const short* __restrict__ Wb,
                                                const float* __restrict__ bias,
                                                float* __restrict__ Out) {
    int mt = blockIdx.x & 63, nt = blockIdx.x >> 6;
    int m0 = mt * 128, n0 = nt * 128;
    int tid = threadIdx.x;
    int w = tid >> 6, l = tid & 63, g = l >> 4, r = l & 15;
    int wm = w >> 2, wn = w & 3;

    __shared__ short As0[128 * 64], As1[128 * 64];
    __shared__ short Bs0[128 * 64], Bs1[128 * 64];

    f32x4 acc[4][2];
#pragma unroll
    for (int i = 0; i < 4; i++)
#pragma unroll
        for (int j = 0; j < 2; j++) acc[i][j] = (f32x4){0.f, 0.f, 0.f, 0.f};

    gemm_k64_db8(A, Wb, As0, As1, Bs0, Bs1, acc, m0, n0);

#pragma unroll
    for (int j = 0; j < 2; j++) {
        int n_g = n0 + wn * 32 + j * 16 + r;
        float bv = bias[n_g];
#pragma unroll
        for (int i = 0; i < 4; i++) {
#pragma unroll
            for (int rr = 0; rr < 4; rr++) {
                int m_g = m0 + wm * 64 + i * 16 + g * 4 + rr;
                Out[(size_t)m_g * HIDN + n_g] = acc[i][j][rr] + bv;
            }
        }
    }
}

// ---------------- flash attention: 512-thread blocks, concurrent paired q-tiles ----------------
// (unchanged from R15: waves 0-3 -> qt=j, waves 4-7 -> qt=15-j, shared K/V stream;
// XCD-local bh decode; un-normalized exp2 softmax.)
__global__ __launch_bounds__(512) void attn_kernel(const short* __restrict__ Qh,
                                                   const short* __restrict__ Kh,
                                                   const short* __restrict__ VhT,
                                                   short* __restrict__ ctx) {
    int bid = blockIdx.x;
    int m = bid >> 8;
    int u = bid & 255;
    int q2 = u >> 6;
    int bh = ((u >> 3) & 7) * 8 + (u & 7);
    int j = m ? (7 - q2) : q2;
    int qtB = 15 - j;
    int tid = threadIdx.x;
    int w = tid >> 6, l = tid & 63;
    int ql = l & 31, hi = l >> 5;
    int wq = w & 3, grp = w >> 2;
    int qt = grp ? qtB : j;

    __shared__ short KV[2][2][64 * 64];  // 32 KB

    const short* Qb = Qh + (size_t)bh * (S_LEN * DHEAD);
    const short* Kb = Kh + (size_t)bh * (S_LEN * DHEAD);
    const short* Vb = VhT + (size_t)bh * (DHEAD * S_LEN);

    int srow = tid >> 3;
    int scol = (tid & 7) * 8;
    int wo = srow * 64 + (scol ^ ((srow & 7) << 3));

    int r0 = ql, r1 = 32 + ql;
    int sw = (ql & 7) << 3;
    int ch = hi * 8;
    int b = bh >> 4, h = bh & 15;

    int q_g = qt * 128 + wq * 32 + ql;
    const short* qp = Qb + (size_t)q_g * DHEAD + hi * 8;
    short8 qf0 = *(const short8*)(qp);
    short8 qf1 = *(const short8*)(qp + 16);
    short8 qf2 = *(const short8*)(qp + 32);
    short8 qf3 = *(const short8*)(qp + 48);

    f32x16 accA, accB;
#pragma unroll
    for (int i = 0; i < 16; ++i) { accA[i] = 0.f; accB[i] = 0.f; }
    float lrun = 0.f;

    int ktp = (qt * 128 + wq * 32) >> 6;
    int nt = 2 * qtB + 2;

    {
        short8 k0 = *(const short8*)(Kb + srow * 64 + scol);
        short8 v0 = *(const short8*)(Vb + (size_t)srow * S_LEN + scol);
        *(short8*)(&KV[0][0][wo]) = k0;
        *(short8*)(&KV[0][1][wo]) = v0;
    }

    for (int kt = 0; kt < nt; ++kt) {
        __syncthreads();
        int cur = kt & 1;
        short8 pk0, pv0;
        bool pf = (kt + 1 < nt);
        if (pf) {
            pk0 = *(const short8*)(Kb + (kt + 1) * (64 * DHEAD) + srow * 64 + scol);
            pv0 = *(const short8*)(Vb + (size_t)srow * S_LEN + (kt + 1) * 64 + scol);
        }
        if (kt <= ktp) {
            const short* Ksb = &KV[cur][0][0];
            const short* Vsb = &KV[cur][1][0];
            f32x16 st0, st1;
#pragma unroll
            for (int i = 0; i < 16; ++i) { st0[i] = 0.f; st1[i] = 0.f; }
            {
                short8 kA, kB;
                kA = *(const short8*)(Ksb + r0 * 64 + ((0 + ch) ^ sw));
                kB = *(const short8*)(Ksb + r1 * 64 + ((0 + ch) ^ sw));
                __builtin_amdgcn_s_setprio(1);
                st0 = __builtin_amdgcn_mfma_f32_32x32x16_bf16(kA, qf0, st0, 0, 0, 0);
                st1 = __builtin_amdgcn_mfma_f32_32x32x16_bf16(kB, qf0, st1, 0, 0, 0);
                __builtin_amdgcn_s_setprio(0);
                kA = *(const short8*)(Ksb + r0 * 64 + ((16 + ch) ^ sw));
                kB = *(const short8*)(Ksb + r1 * 64 + ((16 + ch) ^ sw));
                __builtin_amdgcn_s_setprio(1);
                st0 = __builtin_amdgcn_mfma_f32_32x32x16_bf16(kA, qf1, st0, 0, 0, 0);
                st1 = __builtin_amdgcn_mfma_f32_32x32x16_bf16(kB, qf1, st1, 0, 0, 0);
                __builtin_amdgcn_s_setprio(0);
                kA = *(const short8*)(Ksb + r0 * 64 + ((32 + ch) ^ sw));
                kB = *(const short8*)(Ksb + r1 * 64 + ((32 + ch) ^ sw));
                __builtin_amdgcn_s_setprio(1);
                st0 = __builtin_amdgcn_mfma_f32_32x32x16_bf16(kA, qf2, st0, 0, 0, 0);
                st1 = __builtin_amdgcn_mfma_f32_32x32x16_bf16(kB, qf2, st1, 0, 0, 0);
                __builtin_amdgcn_s_setprio(0);
                kA = *(const short8*)(Ksb + r0 * 64 + ((48 + ch) ^ sw));
                kB = *(const short8*)(Ksb + r1 * 64 + ((48 + ch) ^ sw));
                __builtin_amdgcn_s_setprio(1);
                st0 = __builtin_amdgcn_mfma_f32_32x32x16_bf16(kA, qf3, st0, 0, 0, 0);
                st1 = __builtin_amdgcn_mfma_f32_32x32x16_bf16(kB, qf3, st1, 0, 0, 0);
                __builtin_amdgcn_s_setprio(0);
            }
            float p[32];
#pragma unroll
            for (int i = 0; i < 16; ++i) { p[i] = st0[i]; p[16 + i] = st1[i]; }
            if (kt == ktp) {
#pragma unroll
                for (int i = 0; i < 32; ++i) {
                    int kl = (i & 3) + 8 * ((i >> 2) & 3) + 32 * (i >> 4) + 4 * hi;
                    if (kt * 64 + kl > q_g) p[i] = -1e30f;
                }
            }
#pragma unroll
            for (int i = 0; i < 32; ++i) p[i] = exp2f(p[i]);
            float t[16];
#pragma unroll
            for (int i = 0; i < 16; ++i) t[i] = p[i] + p[i + 16];
#pragma unroll
            for (int i = 0; i < 8; ++i) t[i] = t[i] + t[i + 8];
#pragma unroll
            for (int i = 0; i < 4; ++i) t[i] = t[i] + t[i + 4];
            float rs = (t[0] + t[1]) + (t[2] + t[3]);
            rs += __shfl_xor(rs, 32);
            lrun += rs;
            {
                unsigned u0 = cvtpk(p[0], p[1]);
                unsigned u1 = cvtpk(p[2], p[3]);
                unsigned u2 = cvtpk(p[4], p[5]);
                unsigned u3 = cvtpk(p[6], p[7]);
                plswap(u0, u2);
                plswap(u1, u3);
                short8 pfA = mk8(u0, u1, u2, u3);
                unsigned u4 = cvtpk(p[8], p[9]);
                unsigned u5 = cvtpk(p[10], p[11]);
                unsigned u6 = cvtpk(p[12], p[13]);
                unsigned u7 = cvtpk(p[14], p[15]);
                plswap(u4, u6);
                plswap(u5, u7);
                short8 pfB = mk8(u4, u5, u6, u7);
                short8 vA0 = *(const short8*)(Vsb + r0 * 64 + ((0 + ch) ^ sw));
                short8 vB0 = *(const short8*)(Vsb + r1 * 64 + ((0 + ch) ^ sw));
                short8 vA1 = *(const short8*)(Vsb + r0 * 64 + ((16 + ch) ^ sw));
                short8 vB1 = *(const short8*)(Vsb + r1 * 64 + ((16 + ch) ^ sw));
                __builtin_amdgcn_s_setprio(1);
                accA = __builtin_amdgcn_mfma_f32_32x32x16_bf16(vA0, pfA, accA, 0, 0, 0);
                accB = __builtin_amdgcn_mfma_f32_32x32x16_bf16(vB0, pfA, accB, 0, 0, 0);
                accA = __builtin_amdgcn_mfma_f32_32x32x16_bf16(vA1, pfB, accA, 0, 0, 0);
                accB = __builtin_amdgcn_mfma_f32_32x32x16_bf16(vB1, pfB, accB, 0, 0, 0);
                __builtin_amdgcn_s_setprio(0);
            }
            {
                unsigned u0 = cvtpk(p[16], p[17]);
                unsigned u1 = cvtpk(p[18], p[19]);
                unsigned u2 = cvtpk(p[20], p[21]);
                unsigned u3 = cvtpk(p[22], p[23]);
                plswap(u0, u2);
                plswap(u1, u3);
                short8 pfC = mk8(u0, u1, u2, u3);
                unsigned u4 = cvtpk(p[24], p[25]);
                unsigned u5 = cvtpk(p[26], p[27]);
                unsigned u6 = cvtpk(p[28], p[29]);
                unsigned u7 = cvtpk(p[30], p[31]);
                plswap(u4, u6);
                plswap(u5, u7);
                short8 pfD = mk8(u4, u5, u6, u7);
                short8 vA2 = *(const short8*)(Vsb + r0 * 64 + ((32 + ch) ^ sw));
                short8 vB2 = *(const short8*)(Vsb + r1 * 64 + ((32 + ch) ^ sw));
                short8 vA3 = *(const short8*)(Vsb + r0 * 64 + ((48 + ch) ^ sw));
                short8 vB3 = *(const short8*)(Vsb + r1 * 64 + ((48 + ch) ^ sw));
                __builtin_amdgcn_s_setprio(1);
                accA = __builtin_amdgcn_mfma_f32_32x32x16_bf16(vA2, pfC, accA, 0, 0, 0);
                accB = __builtin_amdgcn_mfma_f32_32x32x16_bf16(vB2, pfC, accB, 0, 0, 0);
                accA = __builtin_amdgcn_mfma_f32_32x32x16_bf16(vA3, pfD, accA, 0, 0, 0);
                accB = __builtin_amdgcn_mfma_f32_32x32x16_bf16(vB3, pfD, accB, 0, 0, 0);
                __builtin_amdgcn_s_setprio(0);
            }
        }
        if (pf) {
            int nb = (kt + 1) & 1;
            *(short8*)(&KV[nb][0][wo]) = pk0;
            *(short8*)(&KV[nb][1][wo]) = pv0;
        }
    }

    float inv = 1.0f / lrun;
    short* cb = ctx + ((size_t)(b * S_LEN + q_g)) * HIDN + h * DHEAD;
#pragma unroll
    for (int i = 0; i < 16; ++i) {
        int d0 = (i & 3) + 8 * (i >> 2) + 4 * hi;
        cb[d0] = f2bf(accA[i] * inv);
        cb[32 + d0] = f2bf(accB[i] * inv);
    }
}

extern "C" void kernel_launch(void* const* d_in, const int* in_sizes, int n_in,
                              void* d_out, int out_size, void* d_ws, size_t ws_size,
                              hipStream_t stream) {
    const float* q  = (const float*)d_in[0];
    const float* k  = (const float*)d_in[1];
    const float* v  = (const float*)d_in[2];
    // d_in[3] = attn_mask: structurally causal, not read.
    const float* Wq = (const float*)d_in[4];
    const float* bq = (const float*)d_in[5];
    const float* Wk = (const float*)d_in[6];
    const float* bk = (const float*)d_in[7];
    const float* Wv = (const float*)d_in[8];
    const float* bv = (const float*)d_in[9];
    const float* Wo = (const float*)d_in[10];
    const float* bo = (const float*)d_in[11];

    char* ws = (char*)d_ws;
    const size_t ACT = (size_t)8192 * 1024 * 2;
    const size_t WSZ = (size_t)1024 * 1024 * 2;
    short* Qh  = (short*)(ws);
    short* Kh  = (short*)(ws + ACT);
    short* VhT = (short*)(ws + 2 * ACT);
    short* qb  = (short*)(ws + 3 * ACT);
    short* kb  = (short*)(ws + 4 * ACT);
    short* vb  = (short*)(ws + 5 * ACT);
    short* ctx = qb;
    short* Wqb = (short*)(ws + 6 * ACT);
    short* Wkb = (short*)(ws + 6 * ACT + WSZ);
    short* Wvb = (short*)(ws + 6 * ACT + 2 * WSZ);
    short* Wob = (short*)(ws + 6 * ACT + 3 * WSZ);

    cvt_all<<<14336, 256, 0, stream>>>(q, k, v, Wq, Wk, Wv, Wo,
                                       qb, kb, vb, Wqb, Wkb, Wvb, Wob);

    const float QSCALE = 0.125f * 1.44269504088896340736f;
    gemm_qkv<<<1536, 512, 0, stream>>>(qb, kb, vb, Wqb, Wkb, Wvb, bq, bk, bv,
                                       Qh, Kh, VhT, QSCALE);

    attn_kernel<<<512, 512, 0, stream>>>(Qh, Kh, VhT, ctx);

    gemm_out<<<512, 512, 0, stream>>>(ctx, Wob, bo, (float*)d_out);
}